// Round 1
// baseline (951.649 us; speedup 1.0000x reference)
//
#include <hip/hip_runtime.h>
#include <math.h>

#define ND 64
#define ED 32
#define GD 32
#define HD 128
#define DOF 6
#define K1 172      // 2*ND + ED + 12
#define K1P 176     // padded row (16B multiple)
#define KG 224      // HD + ND + GD
#define NOUT 70     // ND + DOF
#define OUTC 77     // 64 + 9 + 3 + 1
#define TD 32       // tile (directions / nodes) per block
#define PI_F 3.14159265358979f

__device__ __forceinline__ void mul33_abt(const float* A, const float* B, float* C) {
    // C = A * B^T
#pragma unroll
    for (int r = 0; r < 3; r++)
#pragma unroll
        for (int c = 0; c < 3; c++)
            C[3 * r + c] = A[3 * r + 0] * B[3 * c + 0] + A[3 * r + 1] * B[3 * c + 1] + A[3 * r + 2] * B[3 * c + 2];
}

__global__ void __launch_bounds__(128)
edge_kernel(const float* __restrict__ xfeat, const float* __restrict__ T_R,
            const float* __restrict__ T_t, const float* __restrict__ edge_feat,
            const float* __restrict__ Tij_R, const float* __restrict__ Tij_t,
            const int* __restrict__ edge_index,
            const float* __restrict__ W1, const float* __restrict__ b1,
            const float* __restrict__ W2, const float* __restrict__ b2,
            float* __restrict__ sums, float* __restrict__ cnt, int E)
{
    __shared__ __align__(16) float fbuf[TD][K1P];
    __shared__ int ss1[TD], ss2[TD], sei[TD], stg[TD];
    const int tid = threadIdx.x;
    const int dir0 = blockIdx.x * TD;
    const int ndir = min(TD, 2 * E - dir0);

    // Phase 1: pose math, one direction per thread (threads 0..ndir-1)
    if (tid < ndir) {
        const int dir = dir0 + tid;
        const bool fwd = (dir < E);
        const int e = fwd ? dir : dir - E;
        const int ni = edge_index[e];
        const int nj = edge_index[E + e];
        float Ri[9], Rj[9], TR[9], ti[3], tj[3], Tt[3];
#pragma unroll
        for (int q = 0; q < 9; q++) { Ri[q] = T_R[9 * ni + q]; Rj[q] = T_R[9 * nj + q]; TR[q] = Tij_R[9 * e + q]; }
#pragma unroll
        for (int q = 0; q < 3; q++) { ti[q] = T_t[3 * ni + q]; tj[q] = T_t[3 * nj + q]; Tt[q] = Tij_t[3 * e + q]; }

        float A[9];
        mul33_abt(Rj, Ri, A);   // A = Rj * Ri^T
        float Re[9], te[3];
        if (fwd) {
            // Reij = A * TR^T ; teij = tj - A*ti - Reij*Tt
            mul33_abt(A, TR, Re);
#pragma unroll
            for (int r = 0; r < 3; r++)
                te[r] = tj[r]
                      - (A[3 * r + 0] * ti[0] + A[3 * r + 1] * ti[1] + A[3 * r + 2] * ti[2])
                      - (Re[3 * r + 0] * Tt[0] + Re[3 * r + 1] * Tt[1] + Re[3 * r + 2] * Tt[2]);
            ss1[tid] = ni; ss2[tid] = nj; stg[tid] = nj;
        } else {
            // Rb = A^T ; Reji = A^T * TR ; teji = ti + A^T*(Tt - tj)
#pragma unroll
            for (int r = 0; r < 3; r++)
#pragma unroll
                for (int c = 0; c < 3; c++)
                    Re[3 * r + c] = A[r] * TR[c] + A[3 + r] * TR[3 + c] + A[6 + r] * TR[6 + c];
            const float d0 = Tt[0] - tj[0], d1 = Tt[1] - tj[1], d2 = Tt[2] - tj[2];
#pragma unroll
            for (int r = 0; r < 3; r++)
                te[r] = ti[r] + A[r] * d0 + A[3 + r] * d1 + A[6 + r] * d2;
            ss1[tid] = nj; ss2[tid] = ni; stg[tid] = ni;
        }
        sei[tid] = e;
#pragma unroll
        for (int r = 0; r < 3; r++) {
            fbuf[tid][160 + 4 * r + 0] = Re[3 * r + 0];
            fbuf[tid][160 + 4 * r + 1] = Re[3 * r + 1];
            fbuf[tid][160 + 4 * r + 2] = Re[3 * r + 2];
            fbuf[tid][160 + 4 * r + 3] = te[r];
        }
    }
    __syncthreads();

    // Phase 2: cooperative copy of xfeat / edge_feat into feature rows
    for (int flat = tid; flat < ndir * 160; flat += 128) {
        const int d = flat / 160;
        const int c = flat - d * 160;
        float v;
        if (c < 64)       v = xfeat[ss1[d] * ND + c];
        else if (c < 128) v = xfeat[ss2[d] * ND + (c - 64)];
        else              v = edge_feat[sei[d] * ED + (c - 128)];
        fbuf[d][c] = v;
    }
    __syncthreads();

    // GEMM1: h1 = relu(f @ W1 + b1); thread k owns column k
    float acc[TD];
#pragma unroll
    for (int d = 0; d < TD; d++) acc[d] = 0.f;
    const float bb1 = b1[tid];
    for (int r = 0; r < K1; r += 4) {
        const float w0 = W1[(r + 0) * HD + tid];
        const float w1 = W1[(r + 1) * HD + tid];
        const float w2 = W1[(r + 2) * HD + tid];
        const float w3 = W1[(r + 3) * HD + tid];
#pragma unroll
        for (int d = 0; d < TD; d++) {
            const float4 f = *(const float4*)&fbuf[d][r];
            acc[d] = fmaf(f.x, w0, acc[d]);
            acc[d] = fmaf(f.y, w1, acc[d]);
            acc[d] = fmaf(f.z, w2, acc[d]);
            acc[d] = fmaf(f.w, w3, acc[d]);
        }
    }
    __syncthreads();
#pragma unroll
    for (int d = 0; d < TD; d++)
        fbuf[d][tid] = fmaxf(acc[d] + bb1, 0.f);
    __syncthreads();

    // GEMM2: h2 = relu(h1 @ W2 + b2)
#pragma unroll
    for (int d = 0; d < TD; d++) acc[d] = 0.f;
    const float bb2 = b2[tid];
    for (int r = 0; r < HD; r += 4) {
        const float w0 = W2[(r + 0) * HD + tid];
        const float w1 = W2[(r + 1) * HD + tid];
        const float w2 = W2[(r + 2) * HD + tid];
        const float w3 = W2[(r + 3) * HD + tid];
#pragma unroll
        for (int d = 0; d < TD; d++) {
            const float4 f = *(const float4*)&fbuf[d][r];
            acc[d] = fmaf(f.x, w0, acc[d]);
            acc[d] = fmaf(f.y, w1, acc[d]);
            acc[d] = fmaf(f.z, w2, acc[d]);
            acc[d] = fmaf(f.w, w3, acc[d]);
        }
    }

    // Scatter: atomic accumulate into sums[target]
#pragma unroll
    for (int d = 0; d < TD; d++) {
        if (d < ndir) {
            const float h2 = fmaxf(acc[d] + bb2, 0.f);
            unsafeAtomicAdd(&sums[(size_t)stg[d] * HD + tid], h2);
        }
    }
    if (tid < ndir) unsafeAtomicAdd(&cnt[stg[tid]], 1.0f);
}

__global__ void __launch_bounds__(128)
node_kernel(const float* __restrict__ xfeat, const float* __restrict__ T_R,
            const float* __restrict__ T_t, const float* __restrict__ u,
            const int* __restrict__ batch,
            const float* __restrict__ W3, const float* __restrict__ b3,
            const float* __restrict__ W4, const float* __restrict__ b4,
            const float* __restrict__ sums, const float* __restrict__ cnt,
            float* __restrict__ out, int Nn)
{
    __shared__ __align__(16) float gbuf[TD][KG];
    __shared__ float tbuf[TD][6];
    const int tid = threadIdx.x;
    const int n0 = blockIdx.x * TD;
    const int nn = min(TD, Nn - n0);

    // Build g = [aggr(128), xfeat(64), u[batch](32)]
    for (int d = 0; d < nn; d++) {
        const int n = n0 + d;
        const float inv = 1.0f / fmaxf(cnt[n], 1.0f);
        gbuf[d][tid] = sums[(size_t)n * HD + tid] * inv;
        if (tid < ND) gbuf[d][HD + tid] = xfeat[n * ND + tid];
        else if (tid < ND + GD) gbuf[d][HD + ND + (tid - ND)] = u[batch[n] * GD + (tid - ND)];
    }
    __syncthreads();

    // GEMM3: hidden = relu(g @ W3 + b3)
    float acc[TD];
#pragma unroll
    for (int d = 0; d < TD; d++) acc[d] = 0.f;
    const float bb3 = b3[tid];
    for (int r = 0; r < KG; r += 4) {
        const float w0 = W3[(r + 0) * HD + tid];
        const float w1 = W3[(r + 1) * HD + tid];
        const float w2 = W3[(r + 2) * HD + tid];
        const float w3 = W3[(r + 3) * HD + tid];
#pragma unroll
        for (int d = 0; d < TD; d++) {
            const float4 g = *(const float4*)&gbuf[d][r];
            acc[d] = fmaf(g.x, w0, acc[d]);
            acc[d] = fmaf(g.y, w1, acc[d]);
            acc[d] = fmaf(g.z, w2, acc[d]);
            acc[d] = fmaf(g.w, w3, acc[d]);
        }
    }
    __syncthreads();
#pragma unroll
    for (int d = 0; d < TD; d++) gbuf[d][tid] = fmaxf(acc[d] + bb3, 0.f);
    __syncthreads();

    // GEMM4: out = hidden @ W4 + b4 (70 cols; threads 0..69)
#pragma unroll
    for (int d = 0; d < TD; d++) acc[d] = 0.f;
    if (tid < NOUT) {
        const float bb4 = b4[tid];
        for (int r = 0; r < HD; r += 4) {
            const float w0 = W4[(r + 0) * NOUT + tid];
            const float w1 = W4[(r + 1) * NOUT + tid];
            const float w2 = W4[(r + 2) * NOUT + tid];
            const float w3 = W4[(r + 3) * NOUT + tid];
#pragma unroll
            for (int d = 0; d < TD; d++) {
                const float4 g = *(const float4*)&gbuf[d][r];
                acc[d] = fmaf(g.x, w0, acc[d]);
                acc[d] = fmaf(g.y, w1, acc[d]);
                acc[d] = fmaf(g.z, w2, acc[d]);
                acc[d] = fmaf(g.w, w3, acc[d]);
            }
        }
        if (tid < ND) {
            for (int d = 0; d < nn; d++) {
                const int n = n0 + d;
                out[(size_t)n * OUTC + tid] = xfeat[n * ND + tid] + (acc[d] + bb4);
            }
        } else {
            for (int d = 0; d < nn; d++) tbuf[d][tid - ND] = acc[d] + bb4;
        }
    }
    __syncthreads();

    // SE(3) epilogue: one node per thread
    if (tid < nn) {
        const int n = n0 + tid;
        const float r0 = tbuf[tid][0], r1 = tbuf[tid][1], r2 = tbuf[tid][2];
        float p0 = tbuf[tid][3], p1 = tbuf[tid][4], p2 = tbuf[tid][5];
        const float th0 = sqrtf(p0 * p0 + p1 * p1 + p2 * p2);
        const float s = PI_F * tanhf(th0 / PI_F) / (th0 + 1e-8f);
        p0 *= s; p1 *= s; p2 *= s;
        const float pp = p0 * p0 + p1 * p1 + p2 * p2;
        const float th = sqrtf(pp + 1e-12f);
        float a, b, c;
        if (th < 1e-4f) { a = 1.f - pp / 6.f; b = 0.5f - pp / 24.f; c = 1.f / 6.f - pp / 120.f; }
        else { const float sn = sinf(th), cs = cosf(th); a = sn / th; b = (1.f - cs) / pp; c = (th - sn) / (pp * th); }
        // R = I + aK + b(pp^T - |p|^2 I);  V = I + bK + c(pp^T - |p|^2 I)
        float Rd[9], V[9];
        Rd[0] = 1.f + b * (p0 * p0 - pp); Rd[1] = -a * p2 + b * p0 * p1; Rd[2] = a * p1 + b * p0 * p2;
        Rd[3] = a * p2 + b * p1 * p0;     Rd[4] = 1.f + b * (p1 * p1 - pp); Rd[5] = -a * p0 + b * p1 * p2;
        Rd[6] = -a * p1 + b * p2 * p0;    Rd[7] = a * p0 + b * p2 * p1;  Rd[8] = 1.f + b * (p2 * p2 - pp);
        V[0] = 1.f + c * (p0 * p0 - pp);  V[1] = -b * p2 + c * p0 * p1;  V[2] = b * p1 + c * p0 * p2;
        V[3] = b * p2 + c * p1 * p0;      V[4] = 1.f + c * (p1 * p1 - pp); V[5] = -b * p0 + c * p1 * p2;
        V[6] = -b * p1 + c * p2 * p0;     V[7] = b * p0 + c * p2 * p1;   V[8] = 1.f + c * (p2 * p2 - pp);
        const float td0 = V[0] * r0 + V[1] * r1 + V[2] * r2;
        const float td1 = V[3] * r0 + V[4] * r1 + V[5] * r2;
        const float td2 = V[6] * r0 + V[7] * r1 + V[8] * r2;
        float TRn[9], Ttn[3];
#pragma unroll
        for (int q = 0; q < 9; q++) TRn[q] = T_R[9 * n + q];
#pragma unroll
        for (int q = 0; q < 3; q++) Ttn[q] = T_t[3 * n + q];
        float* o = out + (size_t)n * OUTC + 64;
#pragma unroll
        for (int r = 0; r < 3; r++)
#pragma unroll
            for (int cc = 0; cc < 3; cc++)
                o[3 * r + cc] = Rd[3 * r + 0] * TRn[cc] + Rd[3 * r + 1] * TRn[3 + cc] + Rd[3 * r + 2] * TRn[6 + cc];
        o[9]  = Rd[0] * Ttn[0] + Rd[1] * Ttn[1] + Rd[2] * Ttn[2] + td0;
        o[10] = Rd[3] * Ttn[0] + Rd[4] * Ttn[1] + Rd[5] * Ttn[2] + td1;
        o[11] = Rd[6] * Ttn[0] + Rd[7] * Ttn[1] + Rd[8] * Ttn[2] + td2;
        o[12] = sqrtf(pp);
    }
}

extern "C" void kernel_launch(void* const* d_in, const int* in_sizes, int n_in,
                              void* d_out, int out_size, void* d_ws, size_t ws_size,
                              hipStream_t stream)
{
    const float* xfeat     = (const float*)d_in[0];
    const float* T_R       = (const float*)d_in[1];
    const float* T_t       = (const float*)d_in[2];
    const float* edge_feat = (const float*)d_in[3];
    const float* Tij_R     = (const float*)d_in[4];
    const float* Tij_t     = (const float*)d_in[5];
    const float* u         = (const float*)d_in[6];
    const int*   edge_index= (const int*)d_in[7];
    const int*   batch     = (const int*)d_in[8];
    const float* W1 = (const float*)d_in[9],  *b1 = (const float*)d_in[10];
    const float* W2 = (const float*)d_in[11], *b2 = (const float*)d_in[12];
    const float* W3 = (const float*)d_in[13], *b3 = (const float*)d_in[14];
    const float* W4 = (const float*)d_in[15], *b4 = (const float*)d_in[16];
    const int N = in_sizes[0] / ND;
    const int E = in_sizes[3] / ED;

    float* sums = (float*)d_ws;
    float* cnt  = sums + (size_t)N * HD;
    hipMemsetAsync(d_ws, 0, ((size_t)N * HD + N) * sizeof(float), stream);

    const int eb = (2 * E + TD - 1) / TD;
    edge_kernel<<<eb, 128, 0, stream>>>(xfeat, T_R, T_t, edge_feat, Tij_R, Tij_t,
                                        edge_index, W1, b1, W2, b2, sums, cnt, E);
    const int nb = (N + TD - 1) / TD;
    node_kernel<<<nb, 128, 0, stream>>>(xfeat, T_R, T_t, u, batch, W3, b3, W4, b4,
                                        sums, cnt, (float*)d_out, N);
}

// Round 2
// 457.946 us; speedup vs baseline: 2.0781x; 2.0781x over previous
//
#include <hip/hip_runtime.h>
#include <math.h>

#define ND 64
#define ED 32
#define GD 32
#define HD 128
#define DOF 6
#define K1 172      // 2*ND + ED + 12
#define K1PAD 192   // padded to 6 chunks of 32
#define KG 224      // HD + ND + GD
#define NOUT 70     // ND + DOF
#define OUTC 77     // 64 + 9 + 3 + 1
#define MT 128      // directions per edge block
#define FP 200      // fbuf pitch in bf16 elems (400B -> bank stride 4, conflict-free-ish)
#define TD 32       // nodes per node block
#define PI_F 3.14159265358979f

typedef short short8 __attribute__((ext_vector_type(8)));
typedef float f32x4  __attribute__((ext_vector_type(4)));

// fp32 -> bf16 bits, round-to-nearest-even (inputs are finite)
__device__ __forceinline__ unsigned short f2b(float f) {
    unsigned int u = __float_as_uint(f);
    u += 0x7fffu + ((u >> 16) & 1u);
    return (unsigned short)(u >> 16);
}

__device__ __forceinline__ void mul33_abt(const float* A, const float* B, float* C) {
    // C = A * B^T
#pragma unroll
    for (int r = 0; r < 3; r++)
#pragma unroll
        for (int c = 0; c < 3; c++)
            C[3 * r + c] = A[3 * r + 0] * B[3 * c + 0] + A[3 * r + 1] * B[3 * c + 1] + A[3 * r + 2] * B[3 * c + 2];
}

// Pack W1 (172x128, zero-pad K to 192) and W2 (128x128) into B-fragment layout:
// off(k,n) = (((kc*8 + nt)*4 + quad)*16 + nl)*8 + j   with k=kc*32+quad*8+j, n=nt*16+nl
__global__ void __launch_bounds__(256)
pack_w(const float* __restrict__ W1, const float* __restrict__ W2,
       unsigned short* __restrict__ W1b, unsigned short* __restrict__ W2b)
{
    int idx = blockIdx.x * 256 + threadIdx.x;
    if (idx < K1PAD * HD) {
        int k = idx >> 7, n = idx & 127;
        float v = (k < K1) ? W1[k * HD + n] : 0.f;
        int kc = k >> 5, kr = k & 31, q = kr >> 3, j = kr & 7;
        W1b[(((kc * 8 + (n >> 4)) * 4 + q) * 16 + (n & 15)) * 8 + j] = f2b(v);
    } else {
        int t = idx - K1PAD * HD;
        if (t < HD * HD) {
            int k = t >> 7, n = t & 127;
            float v = W2[k * HD + n];
            int kc = k >> 5, kr = k & 31, q = kr >> 3, j = kr & 7;
            W2b[(((kc * 8 + (n >> 4)) * 4 + q) * 16 + (n & 15)) * 8 + j] = f2b(v);
        }
    }
}

__global__ void __launch_bounds__(256, 3)
edge_kernel(const float* __restrict__ xfeat, const float* __restrict__ T_R,
            const float* __restrict__ T_t, const float* __restrict__ edge_feat,
            const float* __restrict__ Tij_R, const float* __restrict__ Tij_t,
            const int* __restrict__ edge_index,
            const unsigned short* __restrict__ W1b, const float* __restrict__ b1,
            const unsigned short* __restrict__ W2b, const float* __restrict__ b2,
            float* __restrict__ sums, float* __restrict__ cnt, int E)
{
    __shared__ unsigned short fbuf[MT * FP];
    __shared__ int ss1[MT], ss2[MT], sei[MT], stg[MT];
    const int tid = threadIdx.x;
    const int dir0 = blockIdx.x * MT;
    const int ndir = min(MT, 2 * E - dir0);

    // ---- Phase 1: pose math, one direction per thread (tid < 128) ----
    if (tid < MT) {
        if (tid < ndir) {
            const int dir = dir0 + tid;
            const bool fwd = (dir < E);
            const int e = fwd ? dir : dir - E;
            const int ni = edge_index[e];
            const int nj = edge_index[E + e];
            float Ri[9], Rj[9], TR[9], ti[3], tj[3], Tt[3];
#pragma unroll
            for (int q = 0; q < 9; q++) { Ri[q] = T_R[9 * ni + q]; Rj[q] = T_R[9 * nj + q]; TR[q] = Tij_R[9 * e + q]; }
#pragma unroll
            for (int q = 0; q < 3; q++) { ti[q] = T_t[3 * ni + q]; tj[q] = T_t[3 * nj + q]; Tt[q] = Tij_t[3 * e + q]; }
            float A[9];
            mul33_abt(Rj, Ri, A);   // A = Rj * Ri^T
            float Re[9], te[3];
            if (fwd) {
                mul33_abt(A, TR, Re);   // Reij = A * TR^T
#pragma unroll
                for (int r = 0; r < 3; r++)
                    te[r] = tj[r]
                          - (A[3*r+0]*ti[0] + A[3*r+1]*ti[1] + A[3*r+2]*ti[2])
                          - (Re[3*r+0]*Tt[0] + Re[3*r+1]*Tt[1] + Re[3*r+2]*Tt[2]);
                ss1[tid] = ni; ss2[tid] = nj; stg[tid] = nj;
            } else {
#pragma unroll
                for (int r = 0; r < 3; r++)
#pragma unroll
                    for (int c = 0; c < 3; c++)
                        Re[3*r+c] = A[r]*TR[c] + A[3+r]*TR[3+c] + A[6+r]*TR[6+c];  // A^T * TR
                const float d0 = Tt[0]-tj[0], d1 = Tt[1]-tj[1], d2 = Tt[2]-tj[2];
#pragma unroll
                for (int r = 0; r < 3; r++)
                    te[r] = ti[r] + A[r]*d0 + A[3+r]*d1 + A[6+r]*d2;
                ss1[tid] = nj; ss2[tid] = ni; stg[tid] = ni;
            }
            sei[tid] = e;
            unsigned short* fr = &fbuf[tid * FP];
#pragma unroll
            for (int r = 0; r < 3; r++) {
                fr[160 + 4*r + 0] = f2b(Re[3*r+0]);
                fr[160 + 4*r + 1] = f2b(Re[3*r+1]);
                fr[160 + 4*r + 2] = f2b(Re[3*r+2]);
                fr[160 + 4*r + 3] = f2b(te[r]);
            }
#pragma unroll
            for (int c = 172; c < K1PAD; c++) fr[c] = 0;
        } else {
            ss1[tid] = 0; ss2[tid] = 0; sei[tid] = 0; stg[tid] = -1;
            unsigned short* fr = &fbuf[tid * FP];
            for (int c = 160; c < K1PAD; c++) fr[c] = 0;
        }
    }
    __syncthreads();

    // ---- Phase 2: stage xfeat/edge_feat as bf16 (2 threads per row, float4 loads) ----
    {
        const int d = tid >> 1;
        const int half = tid & 1;
        const int s1 = ss1[d], s2 = ss2[d], se = sei[d];
        for (int gg = 0; gg < 20; gg++) {
            const int c4 = (half * 20 + gg) * 4;
            float4 v;
            if (c4 < 64)        v = *(const float4*)&xfeat[s1 * ND + c4];
            else if (c4 < 128)  v = *(const float4*)&xfeat[s2 * ND + (c4 - 64)];
            else                v = *(const float4*)&edge_feat[se * ED + (c4 - 128)];
            ushort4 o; o.x = f2b(v.x); o.y = f2b(v.y); o.z = f2b(v.z); o.w = f2b(v.w);
            *(ushort4*)&fbuf[d * FP + c4] = o;
        }
    }
    __syncthreads();

    // ---- wave-level MFMA GEMMs: each wave owns 32 rows (2 x 16-row tiles) ----
    const int wv = tid >> 6;
    const int lane = tid & 63;
    const int nl = lane & 15;
    const int quad = lane >> 4;
    const int m0w = wv * 32;
    const int laneoff = quad * 128 + nl * 8;   // per-lane offset in packed W chunk (512 elems per (kc,nt))

    float bias1[8], bias2[8];
#pragma unroll
    for (int nt = 0; nt < 8; nt++) { bias1[nt] = b1[nt * 16 + nl]; bias2[nt] = b2[nt * 16 + nl]; }

    f32x4 acc[2][8];
#pragma unroll
    for (int rt = 0; rt < 2; rt++)
#pragma unroll
        for (int nt = 0; nt < 8; nt++) acc[rt][nt] = (f32x4)0.f;

    // GEMM1: h1 = relu(f @ W1 + b1), K = 192
#pragma unroll
    for (int kc = 0; kc < 6; kc++) {
        short8 a0 = *(const short8*)&fbuf[(m0w +  0 + nl) * FP + kc * 32 + quad * 8];
        short8 a1 = *(const short8*)&fbuf[(m0w + 16 + nl) * FP + kc * 32 + quad * 8];
#pragma unroll
        for (int nt = 0; nt < 8; nt++) {
            short8 b = *(const short8*)(W1b + (kc * 8 + nt) * 512 + laneoff);
            acc[0][nt] = __builtin_amdgcn_mfma_f32_16x16x32_bf16(a0, b, acc[0][nt], 0, 0, 0);
            acc[1][nt] = __builtin_amdgcn_mfma_f32_16x16x32_bf16(a1, b, acc[1][nt], 0, 0, 0);
        }
    }
    // bias + relu + store h1 into fbuf cols [0,128) (own rows only -> no barrier)
#pragma unroll
    for (int rt = 0; rt < 2; rt++)
#pragma unroll
        for (int nt = 0; nt < 8; nt++) {
            const int col = nt * 16 + nl;
#pragma unroll
            for (int r = 0; r < 4; r++) {
                const int row = m0w + rt * 16 + quad * 4 + r;
                fbuf[row * FP + col] = f2b(fmaxf(acc[rt][nt][r] + bias1[nt], 0.f));
            }
        }

    // GEMM2: h2 = relu(h1 @ W2 + b2), K = 128
#pragma unroll
    for (int rt = 0; rt < 2; rt++)
#pragma unroll
        for (int nt = 0; nt < 8; nt++) acc[rt][nt] = (f32x4)0.f;
#pragma unroll
    for (int kc = 0; kc < 4; kc++) {
        short8 a0 = *(const short8*)&fbuf[(m0w +  0 + nl) * FP + kc * 32 + quad * 8];
        short8 a1 = *(const short8*)&fbuf[(m0w + 16 + nl) * FP + kc * 32 + quad * 8];
#pragma unroll
        for (int nt = 0; nt < 8; nt++) {
            short8 b = *(const short8*)(W2b + (kc * 8 + nt) * 512 + laneoff);
            acc[0][nt] = __builtin_amdgcn_mfma_f32_16x16x32_bf16(a0, b, acc[0][nt], 0, 0, 0);
            acc[1][nt] = __builtin_amdgcn_mfma_f32_16x16x32_bf16(a1, b, acc[1][nt], 0, 0, 0);
        }
    }

    // scatter: relu + atomic accumulate
    int tg[2][4];
#pragma unroll
    for (int rt = 0; rt < 2; rt++)
#pragma unroll
        for (int r = 0; r < 4; r++) tg[rt][r] = stg[m0w + rt * 16 + quad * 4 + r];
#pragma unroll
    for (int rt = 0; rt < 2; rt++)
#pragma unroll
        for (int nt = 0; nt < 8; nt++) {
            const int col = nt * 16 + nl;
#pragma unroll
            for (int r = 0; r < 4; r++) {
                const int t = tg[rt][r];
                if (t >= 0)
                    unsafeAtomicAdd(&sums[(size_t)t * HD + col], fmaxf(acc[rt][nt][r] + bias2[nt], 0.f));
            }
        }
    if (tid < MT && stg[tid] >= 0) unsafeAtomicAdd(&cnt[stg[tid]], 1.0f);
}

__global__ void __launch_bounds__(128)
node_kernel(const float* __restrict__ xfeat, const float* __restrict__ T_R,
            const float* __restrict__ T_t, const float* __restrict__ u,
            const int* __restrict__ batch,
            const float* __restrict__ W3, const float* __restrict__ b3,
            const float* __restrict__ W4, const float* __restrict__ b4,
            const float* __restrict__ sums, const float* __restrict__ cnt,
            float* __restrict__ out, int Nn)
{
    __shared__ __align__(16) float gbuf[TD][KG];
    __shared__ float tbuf[TD][6];
    const int tid = threadIdx.x;
    const int n0 = blockIdx.x * TD;
    const int nn = min(TD, Nn - n0);

    for (int d = 0; d < nn; d++) {
        const int n = n0 + d;
        const float inv = 1.0f / fmaxf(cnt[n], 1.0f);
        gbuf[d][tid] = sums[(size_t)n * HD + tid] * inv;
        if (tid < ND) gbuf[d][HD + tid] = xfeat[n * ND + tid];
        else if (tid < ND + GD) gbuf[d][HD + ND + (tid - ND)] = u[batch[n] * GD + (tid - ND)];
    }
    __syncthreads();

    float acc[TD];
#pragma unroll
    for (int d = 0; d < TD; d++) acc[d] = 0.f;
    const float bb3 = b3[tid];
    for (int r = 0; r < KG; r += 4) {
        const float w0 = W3[(r + 0) * HD + tid];
        const float w1 = W3[(r + 1) * HD + tid];
        const float w2 = W3[(r + 2) * HD + tid];
        const float w3 = W3[(r + 3) * HD + tid];
#pragma unroll
        for (int d = 0; d < TD; d++) {
            const float4 g = *(const float4*)&gbuf[d][r];
            acc[d] = fmaf(g.x, w0, acc[d]);
            acc[d] = fmaf(g.y, w1, acc[d]);
            acc[d] = fmaf(g.z, w2, acc[d]);
            acc[d] = fmaf(g.w, w3, acc[d]);
        }
    }
    __syncthreads();
#pragma unroll
    for (int d = 0; d < TD; d++) gbuf[d][tid] = fmaxf(acc[d] + bb3, 0.f);
    __syncthreads();

#pragma unroll
    for (int d = 0; d < TD; d++) acc[d] = 0.f;
    if (tid < NOUT) {
        const float bb4 = b4[tid];
        for (int r = 0; r < HD; r += 4) {
            const float w0 = W4[(r + 0) * NOUT + tid];
            const float w1 = W4[(r + 1) * NOUT + tid];
            const float w2 = W4[(r + 2) * NOUT + tid];
            const float w3 = W4[(r + 3) * NOUT + tid];
#pragma unroll
            for (int d = 0; d < TD; d++) {
                const float4 g = *(const float4*)&gbuf[d][r];
                acc[d] = fmaf(g.x, w0, acc[d]);
                acc[d] = fmaf(g.y, w1, acc[d]);
                acc[d] = fmaf(g.z, w2, acc[d]);
                acc[d] = fmaf(g.w, w3, acc[d]);
            }
        }
        if (tid < ND) {
            for (int d = 0; d < nn; d++) {
                const int n = n0 + d;
                out[(size_t)n * OUTC + tid] = xfeat[n * ND + tid] + (acc[d] + bb4);
            }
        } else {
            for (int d = 0; d < nn; d++) tbuf[d][tid - ND] = acc[d] + bb4;
        }
    }
    __syncthreads();

    if (tid < nn) {
        const int n = n0 + tid;
        const float r0 = tbuf[tid][0], r1 = tbuf[tid][1], r2 = tbuf[tid][2];
        float p0 = tbuf[tid][3], p1 = tbuf[tid][4], p2 = tbuf[tid][5];
        const float th0 = sqrtf(p0*p0 + p1*p1 + p2*p2);
        const float s = PI_F * tanhf(th0 / PI_F) / (th0 + 1e-8f);
        p0 *= s; p1 *= s; p2 *= s;
        const float pp = p0*p0 + p1*p1 + p2*p2;
        const float th = sqrtf(pp + 1e-12f);
        float a, b, c;
        if (th < 1e-4f) { a = 1.f - pp/6.f; b = 0.5f - pp/24.f; c = 1.f/6.f - pp/120.f; }
        else { const float sn = sinf(th), cs = cosf(th); a = sn/th; b = (1.f-cs)/pp; c = (th-sn)/(pp*th); }
        float Rd[9], V[9];
        Rd[0]=1.f+b*(p0*p0-pp); Rd[1]=-a*p2+b*p0*p1; Rd[2]= a*p1+b*p0*p2;
        Rd[3]= a*p2+b*p1*p0;    Rd[4]=1.f+b*(p1*p1-pp); Rd[5]=-a*p0+b*p1*p2;
        Rd[6]=-a*p1+b*p2*p0;    Rd[7]= a*p0+b*p2*p1;  Rd[8]=1.f+b*(p2*p2-pp);
        V[0]=1.f+c*(p0*p0-pp);  V[1]=-b*p2+c*p0*p1;   V[2]= b*p1+c*p0*p2;
        V[3]= b*p2+c*p1*p0;     V[4]=1.f+c*(p1*p1-pp); V[5]=-b*p0+c*p1*p2;
        V[6]=-b*p1+c*p2*p0;     V[7]= b*p0+c*p2*p1;   V[8]=1.f+c*(p2*p2-pp);
        const float td0 = V[0]*r0 + V[1]*r1 + V[2]*r2;
        const float td1 = V[3]*r0 + V[4]*r1 + V[5]*r2;
        const float td2 = V[6]*r0 + V[7]*r1 + V[8]*r2;
        float TRn[9], Ttn[3];
#pragma unroll
        for (int q = 0; q < 9; q++) TRn[q] = T_R[9*n+q];
#pragma unroll
        for (int q = 0; q < 3; q++) Ttn[q] = T_t[3*n+q];
        float* o = out + (size_t)n * OUTC + 64;
#pragma unroll
        for (int r = 0; r < 3; r++)
#pragma unroll
            for (int cc = 0; cc < 3; cc++)
                o[3*r+cc] = Rd[3*r+0]*TRn[cc] + Rd[3*r+1]*TRn[3+cc] + Rd[3*r+2]*TRn[6+cc];
        o[9]  = Rd[0]*Ttn[0] + Rd[1]*Ttn[1] + Rd[2]*Ttn[2] + td0;
        o[10] = Rd[3]*Ttn[0] + Rd[4]*Ttn[1] + Rd[5]*Ttn[2] + td1;
        o[11] = Rd[6]*Ttn[0] + Rd[7]*Ttn[1] + Rd[8]*Ttn[2] + td2;
        o[12] = sqrtf(pp);
    }
}

extern "C" void kernel_launch(void* const* d_in, const int* in_sizes, int n_in,
                              void* d_out, int out_size, void* d_ws, size_t ws_size,
                              hipStream_t stream)
{
    const float* xfeat     = (const float*)d_in[0];
    const float* T_R       = (const float*)d_in[1];
    const float* T_t       = (const float*)d_in[2];
    const float* edge_feat = (const float*)d_in[3];
    const float* Tij_R     = (const float*)d_in[4];
    const float* Tij_t     = (const float*)d_in[5];
    const float* u         = (const float*)d_in[6];
    const int*   edge_index= (const int*)d_in[7];
    const int*   batch     = (const int*)d_in[8];
    const float* W1 = (const float*)d_in[9],  *b1 = (const float*)d_in[10];
    const float* W2 = (const float*)d_in[11], *b2 = (const float*)d_in[12];
    const float* W3 = (const float*)d_in[13], *b3 = (const float*)d_in[14];
    const float* W4 = (const float*)d_in[15], *b4 = (const float*)d_in[16];
    const int N = in_sizes[0] / ND;
    const int E = in_sizes[3] / ED;

    // ws layout: [W1b bf16 192*128][W2b bf16 128*128][sums N*128 f32][cnt N f32]
    unsigned short* W1b = (unsigned short*)d_ws;
    unsigned short* W2b = W1b + K1PAD * HD;
    float* sums = (float*)((char*)d_ws + (K1PAD * HD + HD * HD) * sizeof(unsigned short));
    float* cnt  = sums + (size_t)N * HD;
    hipMemsetAsync(sums, 0, ((size_t)N * HD + N) * sizeof(float), stream);

    pack_w<<<(K1PAD * HD + HD * HD + 255) / 256, 256, 0, stream>>>(W1, W2, W1b, W2b);

    const int eb = (2 * E + MT - 1) / MT;
    edge_kernel<<<eb, 256, 0, stream>>>(xfeat, T_R, T_t, edge_feat, Tij_R, Tij_t,
                                        edge_index, W1b, b1, W2b, b2, sums, cnt, E);
    const int nb = (N + TD - 1) / TD;
    node_kernel<<<nb, 128, 0, stream>>>(xfeat, T_R, T_t, u, batch, W3, b3, W4, b4,
                                        sums, cnt, (float*)d_out, N);
}

// Round 3
// 438.518 us; speedup vs baseline: 2.1701x; 1.0443x over previous
//
#include <hip/hip_runtime.h>
#include <math.h>

#define ND 64
#define ED 32
#define GD 32
#define HD 128
#define DOF 6
#define K1 172      // 2*ND + ED + 12
#define K1PAD 192   // padded to 6 chunks of 32
#define KG 224      // HD + ND + GD
#define NOUT 70     // ND + DOF
#define OUTC 77     // 64 + 9 + 3 + 1
#define MT 128      // directions per edge block
#define FP 200      // fbuf pitch in bf16 (400B -> dword bank stride 4; 2-way on b128 reads = free)
#define TD 32       // nodes per node block
#define MAXD 96     // per-node direction list capacity (max in-degree ~ Poisson(20); P(>96) ~ 0)
#define PI_F 3.14159265358979f

typedef short short8 __attribute__((ext_vector_type(8)));
typedef float f32x4  __attribute__((ext_vector_type(4)));

// fp32 -> bf16 bits, round-to-nearest-even
__device__ __forceinline__ unsigned short f2b(float f) {
    unsigned int u = __float_as_uint(f);
    u += 0x7fffu + ((u >> 16) & 1u);
    return (unsigned short)(u >> 16);
}
__device__ __forceinline__ float b2f(unsigned short b) {
    return __uint_as_float(((unsigned int)b) << 16);
}

__device__ __forceinline__ void mul33_abt(const float* A, const float* B, float* C) {
    // C = A * B^T
#pragma unroll
    for (int r = 0; r < 3; r++)
#pragma unroll
        for (int c = 0; c < 3; c++)
            C[3 * r + c] = A[3 * r + 0] * B[3 * c + 0] + A[3 * r + 1] * B[3 * c + 1] + A[3 * r + 2] * B[3 * c + 2];
}

// Pack W1 (172x128, zero-pad K to 192) and W2 (128x128) into MFMA B-fragment layout:
// off(k,n) = (((kc*8 + nt)*4 + quad)*16 + nl)*8 + j  with k=kc*32+quad*8+j, n=nt*16+nl
__global__ void __launch_bounds__(256)
pack_w(const float* __restrict__ W1, const float* __restrict__ W2,
       unsigned short* __restrict__ W1b, unsigned short* __restrict__ W2b)
{
    int idx = blockIdx.x * 256 + threadIdx.x;
    if (idx < K1PAD * HD) {
        int k = idx >> 7, n = idx & 127;
        float v = (k < K1) ? W1[k * HD + n] : 0.f;
        int kc = k >> 5, kr = k & 31, q = kr >> 3, j = kr & 7;
        W1b[(((kc * 8 + (n >> 4)) * 4 + q) * 16 + (n & 15)) * 8 + j] = f2b(v);
    } else {
        int t = idx - K1PAD * HD;
        if (t < HD * HD) {
            int k = t >> 7, n = t & 127;
            float v = W2[k * HD + n];
            int kc = k >> 5, kr = k & 31, q = kr >> 3, j = kr & 7;
            W2b[(((kc * 8 + (n >> 4)) * 4 + q) * 16 + (n & 15)) * 8 + j] = f2b(v);
        }
    }
}

// Per-node direction lists (CSR without offsets: fixed MAXD stride).
__global__ void __launch_bounds__(256)
build_csr(const int* __restrict__ edge_index, int* __restrict__ cnti,
          int* __restrict__ list, int E)
{
    int d = blockIdx.x * 256 + threadIdx.x;
    if (d >= 2 * E) return;
    const int tgt = (d < E) ? edge_index[E + d] : edge_index[d - E];
    const int slot = atomicAdd(&cnti[tgt], 1);
    if (slot < MAXD) list[(size_t)tgt * MAXD + slot] = d;
}

__global__ void __launch_bounds__(256, 3)
edge_kernel(const float* __restrict__ xfeat, const float* __restrict__ T_R,
            const float* __restrict__ T_t, const float* __restrict__ edge_feat,
            const float* __restrict__ Tij_R, const float* __restrict__ Tij_t,
            const int* __restrict__ edge_index,
            const unsigned short* __restrict__ W1b, const float* __restrict__ b1,
            const unsigned short* __restrict__ W2b, const float* __restrict__ b2,
            unsigned short* __restrict__ hbuf, int E)
{
    __shared__ unsigned short fbuf[MT * FP];
    const int tid = threadIdx.x;
    const int dir0 = blockIdx.x * MT;
    const int ndir = min(MT, 2 * E - dir0);

    // ---- Fused phase: all 256 threads stage xfeat/edge_feat (2 threads/row);
    //      threads 0..127 additionally do pose math for their direction. ----
    {
        const int r = tid >> 1;
        const int half = tid & 1;
        const int drow = dir0 + r;
        const bool valid = (r < ndir);
        int s1 = 0, s2 = 0, er = 0;
        if (valid) {
            const bool fwd = (drow < E);
            er = fwd ? drow : drow - E;
            const int ni = edge_index[er];
            const int nj = edge_index[E + er];
            s1 = fwd ? ni : nj;
            s2 = fwd ? nj : ni;
        }
#pragma unroll
        for (int gg = 0; gg < 20; gg++) {
            const int c4 = (half * 20 + gg) * 4;
            float4 v;
            if (c4 < 64)        v = *(const float4*)&xfeat[s1 * ND + c4];
            else if (c4 < 128)  v = *(const float4*)&xfeat[s2 * ND + (c4 - 64)];
            else                v = *(const float4*)&edge_feat[er * ED + (c4 - 128)];
            ushort4 o; o.x = f2b(v.x); o.y = f2b(v.y); o.z = f2b(v.z); o.w = f2b(v.w);
            *(ushort4*)&fbuf[r * FP + c4] = o;
        }
    }
    if (tid < MT && tid < ndir) {
        const int dir = dir0 + tid;
        const bool fwd = (dir < E);
        const int e = fwd ? dir : dir - E;
        const int ni = edge_index[e];
        const int nj = edge_index[E + e];
        float Ri[9], Rj[9], TR[9], ti[3], tj[3], Tt[3];
#pragma unroll
        for (int q = 0; q < 9; q++) { Ri[q] = T_R[9 * ni + q]; Rj[q] = T_R[9 * nj + q]; TR[q] = Tij_R[9 * e + q]; }
#pragma unroll
        for (int q = 0; q < 3; q++) { ti[q] = T_t[3 * ni + q]; tj[q] = T_t[3 * nj + q]; Tt[q] = Tij_t[3 * e + q]; }
        float A[9];
        mul33_abt(Rj, Ri, A);   // A = Rj * Ri^T
        float Re[9], te[3];
        if (fwd) {
            mul33_abt(A, TR, Re);   // Reij = A * TR^T
#pragma unroll
            for (int r = 0; r < 3; r++)
                te[r] = tj[r]
                      - (A[3*r+0]*ti[0] + A[3*r+1]*ti[1] + A[3*r+2]*ti[2])
                      - (Re[3*r+0]*Tt[0] + Re[3*r+1]*Tt[1] + Re[3*r+2]*Tt[2]);
        } else {
#pragma unroll
            for (int r = 0; r < 3; r++)
#pragma unroll
                for (int c = 0; c < 3; c++)
                    Re[3*r+c] = A[r]*TR[c] + A[3+r]*TR[3+c] + A[6+r]*TR[6+c];  // A^T * TR
            const float d0 = Tt[0]-tj[0], d1 = Tt[1]-tj[1], d2 = Tt[2]-tj[2];
#pragma unroll
            for (int r = 0; r < 3; r++)
                te[r] = ti[r] + A[r]*d0 + A[3+r]*d1 + A[6+r]*d2;
        }
        unsigned short* fr = &fbuf[tid * FP];
#pragma unroll
        for (int r = 0; r < 3; r++) {
            fr[160 + 4*r + 0] = f2b(Re[3*r+0]);
            fr[160 + 4*r + 1] = f2b(Re[3*r+1]);
            fr[160 + 4*r + 2] = f2b(Re[3*r+2]);
            fr[160 + 4*r + 3] = f2b(te[r]);
        }
#pragma unroll
        for (int c = 172; c < K1PAD; c++) fr[c] = 0;
    }
    __syncthreads();

    // ---- wave-level MFMA GEMMs: each wave owns 32 rows (2 x 16-row tiles) ----
    const int wv = tid >> 6;
    const int lane = tid & 63;
    const int nl = lane & 15;
    const int quad = lane >> 4;
    const int m0w = wv * 32;
    const int laneoff = quad * 128 + nl * 8;

    float bias1[8], bias2[8];
#pragma unroll
    for (int nt = 0; nt < 8; nt++) { bias1[nt] = b1[nt * 16 + nl]; bias2[nt] = b2[nt * 16 + nl]; }

    f32x4 acc[2][8];
#pragma unroll
    for (int rt = 0; rt < 2; rt++)
#pragma unroll
        for (int nt = 0; nt < 8; nt++) acc[rt][nt] = (f32x4)0.f;

    // GEMM1: h1 = relu(f @ W1 + b1), K = 192
#pragma unroll
    for (int kc = 0; kc < 6; kc++) {
        short8 a0 = *(const short8*)&fbuf[(m0w +  0 + nl) * FP + kc * 32 + quad * 8];
        short8 a1 = *(const short8*)&fbuf[(m0w + 16 + nl) * FP + kc * 32 + quad * 8];
#pragma unroll
        for (int nt = 0; nt < 8; nt++) {
            short8 b = *(const short8*)(W1b + (kc * 8 + nt) * 512 + laneoff);
            acc[0][nt] = __builtin_amdgcn_mfma_f32_16x16x32_bf16(a0, b, acc[0][nt], 0, 0, 0);
            acc[1][nt] = __builtin_amdgcn_mfma_f32_16x16x32_bf16(a1, b, acc[1][nt], 0, 0, 0);
        }
    }
    // bias + relu + store h1 into fbuf cols [0,128) (own rows only -> no barrier)
#pragma unroll
    for (int rt = 0; rt < 2; rt++)
#pragma unroll
        for (int nt = 0; nt < 8; nt++) {
            const int col = nt * 16 + nl;
#pragma unroll
            for (int r = 0; r < 4; r++) {
                const int row = m0w + rt * 16 + quad * 4 + r;
                fbuf[row * FP + col] = f2b(fmaxf(acc[rt][nt][r] + bias1[nt], 0.f));
            }
        }

    // GEMM2: h2 = relu(h1 @ W2 + b2), K = 128
#pragma unroll
    for (int rt = 0; rt < 2; rt++)
#pragma unroll
        for (int nt = 0; nt < 8; nt++) acc[rt][nt] = (f32x4)0.f;
#pragma unroll
    for (int kc = 0; kc < 4; kc++) {
        short8 a0 = *(const short8*)&fbuf[(m0w +  0 + nl) * FP + kc * 32 + quad * 8];
        short8 a1 = *(const short8*)&fbuf[(m0w + 16 + nl) * FP + kc * 32 + quad * 8];
#pragma unroll
        for (int nt = 0; nt < 8; nt++) {
            short8 b = *(const short8*)(W2b + (kc * 8 + nt) * 512 + laneoff);
            acc[0][nt] = __builtin_amdgcn_mfma_f32_16x16x32_bf16(a0, b, acc[0][nt], 0, 0, 0);
            acc[1][nt] = __builtin_amdgcn_mfma_f32_16x16x32_bf16(a1, b, acc[1][nt], 0, 0, 0);
        }
    }

    // relu + plain bf16 stores to hbuf (fire-and-forget; no atomics)
#pragma unroll
    for (int rt = 0; rt < 2; rt++)
#pragma unroll
        for (int r = 0; r < 4; r++) {
            const int m = m0w + rt * 16 + quad * 4 + r;
            if (m < ndir) {
                unsigned short* hrow = hbuf + (size_t)(dir0 + m) * HD;
#pragma unroll
                for (int nt = 0; nt < 8; nt++)
                    hrow[nt * 16 + nl] = f2b(fmaxf(acc[rt][nt][r] + bias2[nt], 0.f));
            }
        }
}

__global__ void __launch_bounds__(128)
node_kernel(const float* __restrict__ xfeat, const float* __restrict__ T_R,
            const float* __restrict__ T_t, const float* __restrict__ u,
            const int* __restrict__ batch,
            const float* __restrict__ W3, const float* __restrict__ b3,
            const float* __restrict__ W4, const float* __restrict__ b4,
            const unsigned short* __restrict__ hbuf, const int* __restrict__ list,
            const int* __restrict__ cnti,
            float* __restrict__ out, int Nn)
{
    __shared__ __align__(16) float gbuf[TD][KG];
    __shared__ float tbuf[TD][6];
    const int tid = threadIdx.x;
    const int n0 = blockIdx.x * TD;
    const int nn = min(TD, Nn - n0);

    // Gather + mean from hbuf via CSR lists; build g = [aggr, xfeat, u[batch]]
    for (int d = 0; d < nn; d++) {
        const int n = n0 + d;
        const int deg = min(cnti[n], MAXD);
        const int* lp = list + (size_t)n * MAXD;
        float acc = 0.f;
        int k = 0;
        for (; k + 4 <= deg; k += 4) {
            const int d0 = lp[k], d1 = lp[k+1], d2 = lp[k+2], d3 = lp[k+3];
            acc += b2f(hbuf[(size_t)d0 * HD + tid]) + b2f(hbuf[(size_t)d1 * HD + tid])
                 + b2f(hbuf[(size_t)d2 * HD + tid]) + b2f(hbuf[(size_t)d3 * HD + tid]);
        }
        for (; k < deg; k++) acc += b2f(hbuf[(size_t)lp[k] * HD + tid]);
        gbuf[d][tid] = acc / (float)max(deg, 1);
        if (tid < ND) gbuf[d][HD + tid] = xfeat[n * ND + tid];
        else if (tid < ND + GD) gbuf[d][HD + ND + (tid - ND)] = u[batch[n] * GD + (tid - ND)];
    }
    __syncthreads();

    float acc[TD];
#pragma unroll
    for (int d = 0; d < TD; d++) acc[d] = 0.f;
    const float bb3 = b3[tid];
    for (int r = 0; r < KG; r += 4) {
        const float w0 = W3[(r + 0) * HD + tid];
        const float w1 = W3[(r + 1) * HD + tid];
        const float w2 = W3[(r + 2) * HD + tid];
        const float w3 = W3[(r + 3) * HD + tid];
#pragma unroll
        for (int d = 0; d < TD; d++) {
            const float4 g = *(const float4*)&gbuf[d][r];
            acc[d] = fmaf(g.x, w0, acc[d]);
            acc[d] = fmaf(g.y, w1, acc[d]);
            acc[d] = fmaf(g.z, w2, acc[d]);
            acc[d] = fmaf(g.w, w3, acc[d]);
        }
    }
    __syncthreads();
#pragma unroll
    for (int d = 0; d < TD; d++) gbuf[d][tid] = fmaxf(acc[d] + bb3, 0.f);
    __syncthreads();

#pragma unroll
    for (int d = 0; d < TD; d++) acc[d] = 0.f;
    if (tid < NOUT) {
        const float bb4 = b4[tid];
        for (int r = 0; r < HD; r += 4) {
            const float w0 = W4[(r + 0) * NOUT + tid];
            const float w1 = W4[(r + 1) * NOUT + tid];
            const float w2 = W4[(r + 2) * NOUT + tid];
            const float w3 = W4[(r + 3) * NOUT + tid];
#pragma unroll
            for (int d = 0; d < TD; d++) {
                const float4 g = *(const float4*)&gbuf[d][r];
                acc[d] = fmaf(g.x, w0, acc[d]);
                acc[d] = fmaf(g.y, w1, acc[d]);
                acc[d] = fmaf(g.z, w2, acc[d]);
                acc[d] = fmaf(g.w, w3, acc[d]);
            }
        }
        if (tid < ND) {
            for (int d = 0; d < nn; d++) {
                const int n = n0 + d;
                out[(size_t)n * OUTC + tid] = xfeat[n * ND + tid] + (acc[d] + bb4);
            }
        } else {
            for (int d = 0; d < nn; d++) tbuf[d][tid - ND] = acc[d] + bb4;
        }
    }
    __syncthreads();

    if (tid < nn) {
        const int n = n0 + tid;
        const float r0 = tbuf[tid][0], r1 = tbuf[tid][1], r2 = tbuf[tid][2];
        float p0 = tbuf[tid][3], p1 = tbuf[tid][4], p2 = tbuf[tid][5];
        const float th0 = sqrtf(p0*p0 + p1*p1 + p2*p2);
        const float s = PI_F * tanhf(th0 / PI_F) / (th0 + 1e-8f);
        p0 *= s; p1 *= s; p2 *= s;
        const float pp = p0*p0 + p1*p1 + p2*p2;
        const float th = sqrtf(pp + 1e-12f);
        float a, b, c;
        if (th < 1e-4f) { a = 1.f - pp/6.f; b = 0.5f - pp/24.f; c = 1.f/6.f - pp/120.f; }
        else { const float sn = sinf(th), cs = cosf(th); a = sn/th; b = (1.f-cs)/pp; c = (th-sn)/(pp*th); }
        float Rd[9], V[9];
        Rd[0]=1.f+b*(p0*p0-pp); Rd[1]=-a*p2+b*p0*p1; Rd[2]= a*p1+b*p0*p2;
        Rd[3]= a*p2+b*p1*p0;    Rd[4]=1.f+b*(p1*p1-pp); Rd[5]=-a*p0+b*p1*p2;
        Rd[6]=-a*p1+b*p2*p0;    Rd[7]= a*p0+b*p2*p1;  Rd[8]=1.f+b*(p2*p2-pp);
        V[0]=1.f+c*(p0*p0-pp);  V[1]=-b*p2+c*p0*p1;   V[2]= b*p1+c*p0*p2;
        V[3]= b*p2+c*p1*p0;     V[4]=1.f+c*(p1*p1-pp); V[5]=-b*p0+c*p1*p2;
        V[6]=-b*p1+c*p2*p0;     V[7]= b*p0+c*p2*p1;   V[8]=1.f+c*(p2*p2-pp);
        const float td0 = V[0]*r0 + V[1]*r1 + V[2]*r2;
        const float td1 = V[3]*r0 + V[4]*r1 + V[5]*r2;
        const float td2 = V[6]*r0 + V[7]*r1 + V[8]*r2;
        float TRn[9], Ttn[3];
#pragma unroll
        for (int q = 0; q < 9; q++) TRn[q] = T_R[9*n+q];
#pragma unroll
        for (int q = 0; q < 3; q++) Ttn[q] = T_t[3*n+q];
        float* o = out + (size_t)n * OUTC + 64;
#pragma unroll
        for (int r = 0; r < 3; r++)
#pragma unroll
            for (int cc = 0; cc < 3; cc++)
                o[3*r+cc] = Rd[3*r+0]*TRn[cc] + Rd[3*r+1]*TRn[3+cc] + Rd[3*r+2]*TRn[6+cc];
        o[9]  = Rd[0]*Ttn[0] + Rd[1]*Ttn[1] + Rd[2]*Ttn[2] + td0;
        o[10] = Rd[3]*Ttn[0] + Rd[4]*Ttn[1] + Rd[5]*Ttn[2] + td1;
        o[11] = Rd[6]*Ttn[0] + Rd[7]*Ttn[1] + Rd[8]*Ttn[2] + td2;
        o[12] = sqrtf(pp);
    }
}

extern "C" void kernel_launch(void* const* d_in, const int* in_sizes, int n_in,
                              void* d_out, int out_size, void* d_ws, size_t ws_size,
                              hipStream_t stream)
{
    const float* xfeat     = (const float*)d_in[0];
    const float* T_R       = (const float*)d_in[1];
    const float* T_t       = (const float*)d_in[2];
    const float* edge_feat = (const float*)d_in[3];
    const float* Tij_R     = (const float*)d_in[4];
    const float* Tij_t     = (const float*)d_in[5];
    const float* u         = (const float*)d_in[6];
    const int*   edge_index= (const int*)d_in[7];
    const int*   batch     = (const int*)d_in[8];
    const float* W1 = (const float*)d_in[9],  *b1 = (const float*)d_in[10];
    const float* W2 = (const float*)d_in[11], *b2 = (const float*)d_in[12];
    const float* W3 = (const float*)d_in[13], *b3 = (const float*)d_in[14];
    const float* W4 = (const float*)d_in[15], *b4 = (const float*)d_in[16];
    const int N = in_sizes[0] / ND;
    const int E = in_sizes[3] / ED;

    // ws layout: [W1b][W2b] bf16 | hbuf 2E*128 bf16 | list N*MAXD int | cnti N int
    char* p = (char*)d_ws;
    unsigned short* W1b = (unsigned short*)p;            p += (size_t)K1PAD * HD * 2;
    unsigned short* W2b = (unsigned short*)p;            p += (size_t)HD * HD * 2;
    unsigned short* hbuf = (unsigned short*)p;           p += (size_t)2 * E * HD * 2;
    int* list = (int*)p;                                 p += (size_t)N * MAXD * 4;
    int* cnti = (int*)p;                                 p += (size_t)N * 4;

    hipMemsetAsync(cnti, 0, (size_t)N * 4, stream);
    pack_w<<<(K1PAD * HD + HD * HD + 255) / 256, 256, 0, stream>>>(W1, W2, W1b, W2b);
    build_csr<<<(2 * E + 255) / 256, 256, 0, stream>>>(edge_index, cnti, list, E);

    const int eb = (2 * E + MT - 1) / MT;
    edge_kernel<<<eb, 256, 0, stream>>>(xfeat, T_R, T_t, edge_feat, Tij_R, Tij_t,
                                        edge_index, W1b, b1, W2b, b2, hbuf, E);
    const int nb = (N + TD - 1) / TD;
    node_kernel<<<nb, 128, 0, stream>>>(xfeat, T_R, T_t, u, batch, W3, b3, W4, b4,
                                        hbuf, list, cnti, (float*)d_out, N);
}

// Round 4
// 311.699 us; speedup vs baseline: 3.0531x; 1.4069x over previous
//
#include <hip/hip_runtime.h>
#include <math.h>

#define ND 64
#define ED 32
#define GD 32
#define HD 128
#define DOF 6
#define K1 172      // 2*ND + ED + 12
#define K1PAD 192   // padded to 6 chunks of 32
#define KG 224      // HD + ND + GD (7 chunks of 32)
#define N4P 80      // W4 cols padded 70 -> 80 (5 n-tiles)
#define NOUT 70     // ND + DOF
#define OUTC 77     // 64 + 9 + 3 + 1
#define MT 128      // directions per edge block
#define FP 200      // edge fbuf pitch (bf16)
#define TD 32       // nodes per node block
#define GP 232      // node gbuf pitch (bf16), 464B rows (16B-aligned)
#define HP 136      // node hidden pitch (bf16), 272B rows (16B-aligned)
#define OP 84       // node obuf pitch (fp32)
#define MAXD 96     // per-node direction list capacity
#define PI_F 3.14159265358979f

typedef short short8 __attribute__((ext_vector_type(8)));
typedef float f32x4  __attribute__((ext_vector_type(4)));

// fp32 -> bf16 bits, round-to-nearest-even
__device__ __forceinline__ unsigned short f2b(float f) {
    unsigned int u = __float_as_uint(f);
    u += 0x7fffu + ((u >> 16) & 1u);
    return (unsigned short)(u >> 16);
}
__device__ __forceinline__ float b2f(unsigned short b) {
    return __uint_as_float(((unsigned int)b) << 16);
}

__device__ __forceinline__ void mul33_abt(const float* A, const float* B, float* C) {
#pragma unroll
    for (int r = 0; r < 3; r++)
#pragma unroll
        for (int c = 0; c < 3; c++)
            C[3*r+c] = A[3*r+0]*B[3*c+0] + A[3*r+1]*B[3*c+1] + A[3*r+2]*B[3*c+2];
}

// Pack all four weight matrices into MFMA B-fragment layout:
// off(k,n) = (((kc*NT + nt)*4 + quad)*16 + nl)*8 + j, k = kc*32 + quad*8 + j, n = nt*16 + nl.
// W3's first 128 K-rows are PERMUTED to match the swizzled hbuf position layout
// (pos p holds original column (p&7)*16 + (p>>3)).
__global__ void __launch_bounds__(256)
pack_w(const float* __restrict__ W1, const float* __restrict__ W2,
       const float* __restrict__ W3, const float* __restrict__ W4,
       unsigned short* __restrict__ W1b, unsigned short* __restrict__ W2b,
       unsigned short* __restrict__ W3b, unsigned short* __restrict__ W4b)
{
    int idx = blockIdx.x * 256 + threadIdx.x;
    if (idx < K1PAD * HD) {
        int k = idx >> 7, n = idx & 127;
        float v = (k < K1) ? W1[k * HD + n] : 0.f;
        int kc = k >> 5, kr = k & 31, q = kr >> 3, j = kr & 7;
        W1b[(((kc * 8 + (n >> 4)) * 4 + q) * 16 + (n & 15)) * 8 + j] = f2b(v);
        return;
    }
    idx -= K1PAD * HD;
    if (idx < HD * HD) {
        int k = idx >> 7, n = idx & 127;
        float v = W2[k * HD + n];
        int kc = k >> 5, kr = k & 31, q = kr >> 3, j = kr & 7;
        W2b[(((kc * 8 + (n >> 4)) * 4 + q) * 16 + (n & 15)) * 8 + j] = f2b(v);
        return;
    }
    idx -= HD * HD;
    if (idx < KG * HD) {
        int k = idx >> 7, n = idx & 127;
        int sk = (k < HD) ? ((k & 7) * 16 + (k >> 3)) : k;   // un-swizzle aggr rows
        float v = W3[sk * HD + n];
        int kc = k >> 5, kr = k & 31, q = kr >> 3, j = kr & 7;
        W3b[(((kc * 8 + (n >> 4)) * 4 + q) * 16 + (n & 15)) * 8 + j] = f2b(v);
        return;
    }
    idx -= KG * HD;
    if (idx < HD * N4P) {
        int k = idx / N4P, n = idx % N4P;
        float v = (n < NOUT) ? W4[k * NOUT + n] : 0.f;
        int kc = k >> 5, kr = k & 31, q = kr >> 3, j = kr & 7;
        W4b[(((kc * 5 + (n >> 4)) * 4 + q) * 16 + (n & 15)) * 8 + j] = f2b(v);
    }
}

// Per-node direction lists (fixed MAXD stride).
__global__ void __launch_bounds__(256)
build_csr(const int* __restrict__ edge_index, int* __restrict__ cnti,
          int* __restrict__ list, int E)
{
    int d = blockIdx.x * 256 + threadIdx.x;
    if (d >= 2 * E) return;
    const int tgt = (d < E) ? edge_index[E + d] : edge_index[d - E];
    const int slot = atomicAdd(&cnti[tgt], 1);
    if (slot < MAXD) list[(size_t)tgt * MAXD + slot] = d;
}

__global__ void __launch_bounds__(256, 3)
edge_kernel(const float* __restrict__ xfeat, const float* __restrict__ T_R,
            const float* __restrict__ T_t, const float* __restrict__ edge_feat,
            const float* __restrict__ Tij_R, const float* __restrict__ Tij_t,
            const int* __restrict__ edge_index,
            const unsigned short* __restrict__ W1b, const float* __restrict__ b1,
            const unsigned short* __restrict__ W2b, const float* __restrict__ b2,
            unsigned short* __restrict__ hbuf, int E)
{
    __shared__ unsigned short fbuf[MT * FP];
    const int tid = threadIdx.x;
    const int dir0 = blockIdx.x * MT;
    const int ndir = min(MT, 2 * E - dir0);

    // Fused staging (all 256 threads, 2/row) + pose math (threads 0..127)
    {
        const int r = tid >> 1;
        const int half = tid & 1;
        const int drow = dir0 + r;
        int s1 = 0, s2 = 0, er = 0;
        if (r < ndir) {
            const bool fwd = (drow < E);
            er = fwd ? drow : drow - E;
            const int ni = edge_index[er];
            const int nj = edge_index[E + er];
            s1 = fwd ? ni : nj;
            s2 = fwd ? nj : ni;
        }
#pragma unroll
        for (int gg = 0; gg < 20; gg++) {
            const int c4 = (half * 20 + gg) * 4;
            float4 v;
            if (c4 < 64)        v = *(const float4*)&xfeat[s1 * ND + c4];
            else if (c4 < 128)  v = *(const float4*)&xfeat[s2 * ND + (c4 - 64)];
            else                v = *(const float4*)&edge_feat[er * ED + (c4 - 128)];
            ushort4 o; o.x = f2b(v.x); o.y = f2b(v.y); o.z = f2b(v.z); o.w = f2b(v.w);
            *(ushort4*)&fbuf[r * FP + c4] = o;
        }
    }
    if (tid < MT && tid < ndir) {
        const int dir = dir0 + tid;
        const bool fwd = (dir < E);
        const int e = fwd ? dir : dir - E;
        const int ni = edge_index[e];
        const int nj = edge_index[E + e];
        float Ri[9], Rj[9], TR[9], ti[3], tj[3], Tt[3];
#pragma unroll
        for (int q = 0; q < 9; q++) { Ri[q] = T_R[9*ni+q]; Rj[q] = T_R[9*nj+q]; TR[q] = Tij_R[9*e+q]; }
#pragma unroll
        for (int q = 0; q < 3; q++) { ti[q] = T_t[3*ni+q]; tj[q] = T_t[3*nj+q]; Tt[q] = Tij_t[3*e+q]; }
        float A[9];
        mul33_abt(Rj, Ri, A);   // A = Rj * Ri^T
        float Re[9], te[3];
        if (fwd) {
            mul33_abt(A, TR, Re);
#pragma unroll
            for (int r = 0; r < 3; r++)
                te[r] = tj[r]
                      - (A[3*r+0]*ti[0] + A[3*r+1]*ti[1] + A[3*r+2]*ti[2])
                      - (Re[3*r+0]*Tt[0] + Re[3*r+1]*Tt[1] + Re[3*r+2]*Tt[2]);
        } else {
#pragma unroll
            for (int r = 0; r < 3; r++)
#pragma unroll
                for (int c = 0; c < 3; c++)
                    Re[3*r+c] = A[r]*TR[c] + A[3+r]*TR[3+c] + A[6+r]*TR[6+c];
            const float d0 = Tt[0]-tj[0], d1 = Tt[1]-tj[1], d2 = Tt[2]-tj[2];
#pragma unroll
            for (int r = 0; r < 3; r++)
                te[r] = ti[r] + A[r]*d0 + A[3+r]*d1 + A[6+r]*d2;
        }
        unsigned short* fr = &fbuf[tid * FP];
#pragma unroll
        for (int r = 0; r < 3; r++) {
            fr[160 + 4*r + 0] = f2b(Re[3*r+0]);
            fr[160 + 4*r + 1] = f2b(Re[3*r+1]);
            fr[160 + 4*r + 2] = f2b(Re[3*r+2]);
            fr[160 + 4*r + 3] = f2b(te[r]);
        }
#pragma unroll
        for (int c = 172; c < K1PAD; c++) fr[c] = 0;
    }
    __syncthreads();

    const int wv = tid >> 6;
    const int lane = tid & 63;
    const int nl = lane & 15;
    const int quad = lane >> 4;
    const int m0w = wv * 32;
    const int laneoff = quad * 128 + nl * 8;

    float bias1[8], bias2[8];
#pragma unroll
    for (int nt = 0; nt < 8; nt++) { bias1[nt] = b1[nt*16 + nl]; bias2[nt] = b2[nt*16 + nl]; }

    f32x4 acc[2][8];
#pragma unroll
    for (int rt = 0; rt < 2; rt++)
#pragma unroll
        for (int nt = 0; nt < 8; nt++) acc[rt][nt] = (f32x4)0.f;

    // GEMM1: K = 192
#pragma unroll
    for (int kc = 0; kc < 6; kc++) {
        short8 a0 = *(const short8*)&fbuf[(m0w +  0 + nl) * FP + kc*32 + quad*8];
        short8 a1 = *(const short8*)&fbuf[(m0w + 16 + nl) * FP + kc*32 + quad*8];
#pragma unroll
        for (int nt = 0; nt < 8; nt++) {
            short8 b = *(const short8*)(W1b + (kc*8 + nt)*512 + laneoff);
            acc[0][nt] = __builtin_amdgcn_mfma_f32_16x16x32_bf16(a0, b, acc[0][nt], 0, 0, 0);
            acc[1][nt] = __builtin_amdgcn_mfma_f32_16x16x32_bf16(a1, b, acc[1][nt], 0, 0, 0);
        }
    }
#pragma unroll
    for (int rt = 0; rt < 2; rt++)
#pragma unroll
        for (int nt = 0; nt < 8; nt++) {
            const int col = nt*16 + nl;
#pragma unroll
            for (int r = 0; r < 4; r++) {
                const int row = m0w + rt*16 + quad*4 + r;
                fbuf[row * FP + col] = f2b(fmaxf(acc[rt][nt][r] + bias1[nt], 0.f));
            }
        }

    // GEMM2: K = 128
#pragma unroll
    for (int rt = 0; rt < 2; rt++)
#pragma unroll
        for (int nt = 0; nt < 8; nt++) acc[rt][nt] = (f32x4)0.f;
#pragma unroll
    for (int kc = 0; kc < 4; kc++) {
        short8 a0 = *(const short8*)&fbuf[(m0w +  0 + nl) * FP + kc*32 + quad*8];
        short8 a1 = *(const short8*)&fbuf[(m0w + 16 + nl) * FP + kc*32 + quad*8];
#pragma unroll
        for (int nt = 0; nt < 8; nt++) {
            short8 b = *(const short8*)(W2b + (kc*8 + nt)*512 + laneoff);
            acc[0][nt] = __builtin_amdgcn_mfma_f32_16x16x32_bf16(a0, b, acc[0][nt], 0, 0, 0);
            acc[1][nt] = __builtin_amdgcn_mfma_f32_16x16x32_bf16(a1, b, acc[1][nt], 0, 0, 0);
        }
    }

    // relu + SWIZZLED packed store: lane's 8 nt values are contiguous at pos nl*8+nt
#pragma unroll
    for (int rt = 0; rt < 2; rt++)
#pragma unroll
        for (int r = 0; r < 4; r++) {
            const int m = m0w + rt*16 + quad*4 + r;
            if (m < ndir) {
                short8 hv;
#pragma unroll
                for (int nt = 0; nt < 8; nt++)
                    hv[nt] = (short)f2b(fmaxf(acc[rt][nt][r] + bias2[nt], 0.f));
                *(short8*)(hbuf + (size_t)(dir0 + m) * HD + nl*8) = hv;
            }
        }
}

__global__ void __launch_bounds__(256)
node_kernel(const float* __restrict__ xfeat, const float* __restrict__ T_R,
            const float* __restrict__ T_t, const float* __restrict__ u,
            const int* __restrict__ batch,
            const unsigned short* __restrict__ W3b, const float* __restrict__ b3,
            const unsigned short* __restrict__ W4b, const float* __restrict__ b4,
            const unsigned short* __restrict__ hbuf, const int* __restrict__ list,
            const int* __restrict__ cnti,
            float* __restrict__ out, int Nn)
{
    __shared__ unsigned short gbuf[TD * GP];   // [aggr(128, swizzled pos) | xfeat(64) | u(32)] bf16
    __shared__ unsigned short hid[TD * HP];    // hidden 32x128 bf16
    __shared__ float obuf[TD * OP];            // out 32x80 fp32
    const int tid = threadIdx.x;
    const int wv = tid >> 6, lane = tid & 63;
    const int n0 = blockIdx.x * TD;
    const int nn = min(TD, Nn - n0);

    // ---- gather+mean: wave wv owns nodes d = wv + 4i; lane covers positions 2*lane, 2*lane+1 ----
#pragma unroll 2
    for (int i = 0; i < 8; i++) {
        const int d = wv + 4*i;
        if (d < nn) {
            const int n = n0 + d;
            const int deg = cnti[n];
            const int degl = min(deg, MAXD);
            const float inv = 1.0f / (float)max(deg, 1);
            const int* lp = list + (size_t)n * MAXD;
            float a0 = 0.f, a1 = 0.f;
            int k = 0;
            for (; k + 2 <= degl; k += 2) {
                const int e0 = lp[k], e1 = lp[k+1];
                const unsigned int v0 = *(const unsigned int*)(hbuf + (size_t)e0 * HD + 2*lane);
                const unsigned int v1 = *(const unsigned int*)(hbuf + (size_t)e1 * HD + 2*lane);
                a0 += b2f((unsigned short)v0) + b2f((unsigned short)v1);
                a1 += b2f((unsigned short)(v0 >> 16)) + b2f((unsigned short)(v1 >> 16));
            }
            if (k < degl) {
                const unsigned int v0 = *(const unsigned int*)(hbuf + (size_t)lp[k] * HD + 2*lane);
                a0 += b2f((unsigned short)v0);
                a1 += b2f((unsigned short)(v0 >> 16));
            }
            const unsigned int pk = (unsigned int)f2b(a0 * inv) | ((unsigned int)f2b(a1 * inv) << 16);
            *(unsigned int*)&gbuf[d * GP + 2*lane] = pk;
        }
    }
    // stage xfeat (pos 128..191) and u[batch] (pos 192..223)
    for (int idx = tid; idx < TD * 24; idx += 256) {
        const int d = idx / 24;
        if (d < nn) {
            const int n = n0 + d;
            const int c4 = (idx % 24) * 4;
            float4 v;
            if (c4 < 64) v = *(const float4*)&xfeat[(size_t)n * ND + c4];
            else         v = *(const float4*)&u[(size_t)batch[n] * GD + (c4 - 64)];
            ushort4 o; o.x = f2b(v.x); o.y = f2b(v.y); o.z = f2b(v.z); o.w = f2b(v.w);
            *(ushort4*)&gbuf[d * GP + 128 + c4] = o;
        }
    }
    __syncthreads();

    const int nl = lane & 15, quad = lane >> 4;
    const int laneoff = quad * 128 + nl * 8;

    // ---- GEMM3 (MFMA): K=224; wave wv computes n-tiles {2wv, 2wv+1} for all 32 rows ----
    f32x4 acc3[2][2];
#pragma unroll
    for (int mt = 0; mt < 2; mt++)
#pragma unroll
        for (int t = 0; t < 2; t++) acc3[mt][t] = (f32x4)0.f;
#pragma unroll
    for (int kc = 0; kc < 7; kc++) {
        short8 A0 = *(const short8*)&gbuf[( 0 + nl) * GP + kc*32 + quad*8];
        short8 A1 = *(const short8*)&gbuf[(16 + nl) * GP + kc*32 + quad*8];
#pragma unroll
        for (int t = 0; t < 2; t++) {
            const int nt = wv*2 + t;
            short8 B = *(const short8*)(W3b + (kc*8 + nt)*512 + laneoff);
            acc3[0][t] = __builtin_amdgcn_mfma_f32_16x16x32_bf16(A0, B, acc3[0][t], 0, 0, 0);
            acc3[1][t] = __builtin_amdgcn_mfma_f32_16x16x32_bf16(A1, B, acc3[1][t], 0, 0, 0);
        }
    }
#pragma unroll
    for (int t = 0; t < 2; t++) {
        const int col = (wv*2 + t)*16 + nl;
        const float bb = b3[col];
#pragma unroll
        for (int mt = 0; mt < 2; mt++)
#pragma unroll
            for (int r = 0; r < 4; r++)
                hid[(mt*16 + quad*4 + r) * HP + col] = f2b(fmaxf(acc3[mt][t][r] + bb, 0.f));
    }
    __syncthreads();

    // ---- GEMM4 (MFMA): K=128, N=80 (5 n-tiles; wave w -> nt=w, wave0 also nt=4) ----
    f32x4 acc4[2][2];
#pragma unroll
    for (int mt = 0; mt < 2; mt++)
#pragma unroll
        for (int t = 0; t < 2; t++) acc4[mt][t] = (f32x4)0.f;
    const int nt1 = (wv == 0) ? 4 : -1;
#pragma unroll
    for (int kc = 0; kc < 4; kc++) {
        short8 A0 = *(const short8*)&hid[( 0 + nl) * HP + kc*32 + quad*8];
        short8 A1 = *(const short8*)&hid[(16 + nl) * HP + kc*32 + quad*8];
        short8 B0 = *(const short8*)(W4b + (kc*5 + wv)*512 + laneoff);
        acc4[0][0] = __builtin_amdgcn_mfma_f32_16x16x32_bf16(A0, B0, acc4[0][0], 0, 0, 0);
        acc4[1][0] = __builtin_amdgcn_mfma_f32_16x16x32_bf16(A1, B0, acc4[1][0], 0, 0, 0);
        if (nt1 >= 0) {
            short8 B1 = *(const short8*)(W4b + (kc*5 + nt1)*512 + laneoff);
            acc4[0][1] = __builtin_amdgcn_mfma_f32_16x16x32_bf16(A0, B1, acc4[0][1], 0, 0, 0);
            acc4[1][1] = __builtin_amdgcn_mfma_f32_16x16x32_bf16(A1, B1, acc4[1][1], 0, 0, 0);
        }
    }
    {
        const int col0 = wv*16 + nl;
        const float bb0 = (col0 < NOUT) ? b4[col0] : 0.f;
#pragma unroll
        for (int mt = 0; mt < 2; mt++)
#pragma unroll
            for (int r = 0; r < 4; r++)
                obuf[(mt*16 + quad*4 + r) * OP + col0] = acc4[mt][0][r] + bb0;
        if (nt1 >= 0) {
            const int col1 = nt1*16 + nl;
            const float bb1 = (col1 < NOUT) ? b4[col1] : 0.f;
#pragma unroll
            for (int mt = 0; mt < 2; mt++)
#pragma unroll
                for (int r = 0; r < 4; r++)
                    obuf[(mt*16 + quad*4 + r) * OP + col1] = acc4[mt][1][r] + bb1;
        }
    }
    __syncthreads();

    // ---- epilogue: xfeat residual ----
    for (int idx = tid; idx < TD * ND; idx += 256) {
        const int d = idx >> 6, c = idx & 63;
        if (d < nn) {
            const int n = n0 + d;
            out[(size_t)n * OUTC + c] = xfeat[(size_t)n * ND + c] + obuf[d * OP + c];
        }
    }
    // ---- SE(3) epilogue: one node per thread ----
    if (tid < nn) {
        const int n = n0 + tid;
        const float r0 = obuf[tid*OP + 64], r1 = obuf[tid*OP + 65], r2 = obuf[tid*OP + 66];
        float p0 = obuf[tid*OP + 67], p1 = obuf[tid*OP + 68], p2 = obuf[tid*OP + 69];
        const float th0 = sqrtf(p0*p0 + p1*p1 + p2*p2);
        const float s = PI_F * tanhf(th0 / PI_F) / (th0 + 1e-8f);
        p0 *= s; p1 *= s; p2 *= s;
        const float pp = p0*p0 + p1*p1 + p2*p2;
        const float th = sqrtf(pp + 1e-12f);
        float a, b, c;
        if (th < 1e-4f) { a = 1.f - pp/6.f; b = 0.5f - pp/24.f; c = 1.f/6.f - pp/120.f; }
        else { const float sn = sinf(th), cs = cosf(th); a = sn/th; b = (1.f-cs)/pp; c = (th-sn)/(pp*th); }
        float Rd[9], V[9];
        Rd[0]=1.f+b*(p0*p0-pp); Rd[1]=-a*p2+b*p0*p1; Rd[2]= a*p1+b*p0*p2;
        Rd[3]= a*p2+b*p1*p0;    Rd[4]=1.f+b*(p1*p1-pp); Rd[5]=-a*p0+b*p1*p2;
        Rd[6]=-a*p1+b*p2*p0;    Rd[7]= a*p0+b*p2*p1;  Rd[8]=1.f+b*(p2*p2-pp);
        V[0]=1.f+c*(p0*p0-pp);  V[1]=-b*p2+c*p0*p1;   V[2]= b*p1+c*p0*p2;
        V[3]= b*p2+c*p1*p0;     V[4]=1.f+c*(p1*p1-pp); V[5]=-b*p0+c*p1*p2;
        V[6]=-b*p1+c*p2*p0;     V[7]= b*p0+c*p2*p1;   V[8]=1.f+c*(p2*p2-pp);
        const float td0 = V[0]*r0 + V[1]*r1 + V[2]*r2;
        const float td1 = V[3]*r0 + V[4]*r1 + V[5]*r2;
        const float td2 = V[6]*r0 + V[7]*r1 + V[8]*r2;
        float TRn[9], Ttn[3];
#pragma unroll
        for (int q = 0; q < 9; q++) TRn[q] = T_R[9*n+q];
#pragma unroll
        for (int q = 0; q < 3; q++) Ttn[q] = T_t[3*n+q];
        float* o = out + (size_t)n * OUTC + 64;
#pragma unroll
        for (int r = 0; r < 3; r++)
#pragma unroll
            for (int cc = 0; cc < 3; cc++)
                o[3*r+cc] = Rd[3*r+0]*TRn[cc] + Rd[3*r+1]*TRn[3+cc] + Rd[3*r+2]*TRn[6+cc];
        o[9]  = Rd[0]*Ttn[0] + Rd[1]*Ttn[1] + Rd[2]*Ttn[2] + td0;
        o[10] = Rd[3]*Ttn[0] + Rd[4]*Ttn[1] + Rd[5]*Ttn[2] + td1;
        o[11] = Rd[6]*Ttn[0] + Rd[7]*Ttn[1] + Rd[8]*Ttn[2] + td2;
        o[12] = sqrtf(pp);
    }
}

extern "C" void kernel_launch(void* const* d_in, const int* in_sizes, int n_in,
                              void* d_out, int out_size, void* d_ws, size_t ws_size,
                              hipStream_t stream)
{
    const float* xfeat     = (const float*)d_in[0];
    const float* T_R       = (const float*)d_in[1];
    const float* T_t       = (const float*)d_in[2];
    const float* edge_feat = (const float*)d_in[3];
    const float* Tij_R     = (const float*)d_in[4];
    const float* Tij_t     = (const float*)d_in[5];
    const float* u         = (const float*)d_in[6];
    const int*   edge_index= (const int*)d_in[7];
    const int*   batch     = (const int*)d_in[8];
    const float* W1 = (const float*)d_in[9],  *b1 = (const float*)d_in[10];
    const float* W2 = (const float*)d_in[11], *b2 = (const float*)d_in[12];
    const float* W3 = (const float*)d_in[13], *b3 = (const float*)d_in[14];
    const float* W4 = (const float*)d_in[15], *b4 = (const float*)d_in[16];
    const int N = in_sizes[0] / ND;
    const int E = in_sizes[3] / ED;

    // ws: [W1b][W2b][W3b][W4b] bf16 | hbuf 2E*128 bf16 | list N*MAXD int | cnti N int
    char* p = (char*)d_ws;
    unsigned short* W1b = (unsigned short*)p;  p += (size_t)K1PAD * HD * 2;
    unsigned short* W2b = (unsigned short*)p;  p += (size_t)HD * HD * 2;
    unsigned short* W3b = (unsigned short*)p;  p += (size_t)KG * HD * 2;
    unsigned short* W4b = (unsigned short*)p;  p += (size_t)HD * N4P * 2;
    unsigned short* hbuf = (unsigned short*)p; p += (size_t)2 * E * HD * 2;
    int* list = (int*)p;                       p += (size_t)N * MAXD * 4;
    int* cnti = (int*)p;

    hipMemsetAsync(cnti, 0, (size_t)N * 4, stream);
    const int packn = K1PAD*HD + HD*HD + KG*HD + HD*N4P;
    pack_w<<<(packn + 255) / 256, 256, 0, stream>>>(W1, W2, W3, W4, W1b, W2b, W3b, W4b);
    build_csr<<<(2 * E + 255) / 256, 256, 0, stream>>>(edge_index, cnti, list, E);

    const int eb = (2 * E + MT - 1) / MT;
    edge_kernel<<<eb, 256, 0, stream>>>(xfeat, T_R, T_t, edge_feat, Tij_R, Tij_t,
                                        edge_index, W1b, b1, W2b, b2, hbuf, E);
    const int nb = (N + TD - 1) / TD;
    node_kernel<<<nb, 256, 0, stream>>>(xfeat, T_R, T_t, u, batch, W3b, b3, W4b, b4,
                                        hbuf, list, cnti, (float*)d_out, N);
}

// Round 5
// 295.797 us; speedup vs baseline: 3.2172x; 1.0538x over previous
//
#include <hip/hip_runtime.h>
#include <math.h>

#define ND 64
#define ED 32
#define GD 32
#define HD 128
#define DOF 6
#define K1 172      // 2*ND + ED + 12
#define K1PAD 192   // padded to 6 chunks of 32
#define KG 224      // HD + ND + GD (7 chunks of 32)
#define N4P 80      // W4 cols padded 70 -> 80 (5 n-tiles)
#define NOUT 70
#define OUTC 77
#define MT 128      // directions per edge block (4 waves x 32)
#define HP1 136     // edge h1 LDS pitch (bf16), 272B = 17*16 (b128-aligned)
#define TDN 16      // nodes per node block
#define GP 232      // node gbuf pitch (bf16)
#define HP 136      // node hidden pitch (bf16)
#define OP 84       // node obuf pitch (fp32)
#define MAXD 96
#define PI_F 3.14159265358979f

typedef short short8 __attribute__((ext_vector_type(8)));
typedef float f32x4  __attribute__((ext_vector_type(4)));

__device__ __forceinline__ unsigned short f2b(float f) {
    unsigned int u = __float_as_uint(f);
    u += 0x7fffu + ((u >> 16) & 1u);
    return (unsigned short)(u >> 16);
}
__device__ __forceinline__ float b2f(unsigned short b) {
    return __uint_as_float(((unsigned int)b) << 16);
}
__device__ __forceinline__ void mul33_abt(const float* A, const float* B, float* C) {
#pragma unroll
    for (int r = 0; r < 3; r++)
#pragma unroll
        for (int c = 0; c < 3; c++)
            C[3*r+c] = A[3*r+0]*B[3*c+0] + A[3*r+1]*B[3*c+1] + A[3*r+2]*B[3*c+2];
}

// Pack weights to MFMA B-fragment layout + pre-convert xfeat/edge_feat to bf16.
// B-frag: off(k,n) = (((kc*NT + nt)*4 + quad)*16 + nl)*8 + j ; k = kc*32+quad*8+j, n = nt*16+nl.
// W3's first 128 K-rows permuted for the swizzled hbuf position layout (pos p <- col (p&7)*16+(p>>3)).
__global__ void __launch_bounds__(256)
prep(const float* __restrict__ W1, const float* __restrict__ W2,
     const float* __restrict__ W3, const float* __restrict__ W4,
     const float* __restrict__ xfeat, const float* __restrict__ edge_feat,
     unsigned short* __restrict__ W1b, unsigned short* __restrict__ W2b,
     unsigned short* __restrict__ W3b, unsigned short* __restrict__ W4b,
     unsigned short* __restrict__ xb, unsigned short* __restrict__ eb,
     int N, int E)
{
    int idx = blockIdx.x * 256 + threadIdx.x;
    if (idx < K1PAD * HD) {
        int k = idx >> 7, n = idx & 127;
        float v = (k < K1) ? W1[k * HD + n] : 0.f;
        int kc = k >> 5, kr = k & 31, q = kr >> 3, j = kr & 7;
        W1b[(((kc * 8 + (n >> 4)) * 4 + q) * 16 + (n & 15)) * 8 + j] = f2b(v);
        return;
    }
    idx -= K1PAD * HD;
    if (idx < HD * HD) {
        int k = idx >> 7, n = idx & 127;
        int kc = k >> 5, kr = k & 31, q = kr >> 3, j = kr & 7;
        W2b[(((kc * 8 + (n >> 4)) * 4 + q) * 16 + (n & 15)) * 8 + j] = f2b(W2[k * HD + n]);
        return;
    }
    idx -= HD * HD;
    if (idx < KG * HD) {
        int k = idx >> 7, n = idx & 127;
        int sk = (k < HD) ? ((k & 7) * 16 + (k >> 3)) : k;
        int kc = k >> 5, kr = k & 31, q = kr >> 3, j = kr & 7;
        W3b[(((kc * 8 + (n >> 4)) * 4 + q) * 16 + (n & 15)) * 8 + j] = f2b(W3[sk * HD + n]);
        return;
    }
    idx -= KG * HD;
    if (idx < HD * N4P) {
        int k = idx / N4P, n = idx % N4P;
        float v = (n < NOUT) ? W4[k * NOUT + n] : 0.f;
        int kc = k >> 5, kr = k & 31, q = kr >> 3, j = kr & 7;
        W4b[(((kc * 5 + (n >> 4)) * 4 + q) * 16 + (n & 15)) * 8 + j] = f2b(v);
        return;
    }
    idx -= HD * N4P;
    const int nx4 = N * ND / 4;
    if (idx < nx4) {
        const float4 v = *(const float4*)&xfeat[idx * 4];
        ushort4 o; o.x = f2b(v.x); o.y = f2b(v.y); o.z = f2b(v.z); o.w = f2b(v.w);
        *(ushort4*)&xb[idx * 4] = o;
        return;
    }
    idx -= nx4;
    if (idx < E * ED / 4) {
        const float4 v = *(const float4*)&edge_feat[idx * 4];
        ushort4 o; o.x = f2b(v.x); o.y = f2b(v.y); o.z = f2b(v.z); o.w = f2b(v.w);
        *(ushort4*)&eb[idx * 4] = o;
    }
}

// Per-direction pose math (bf16, padded to 16) + CSR target lists.
__global__ void __launch_bounds__(256)
pose_csr(const float* __restrict__ T_R, const float* __restrict__ T_t,
         const float* __restrict__ Tij_R, const float* __restrict__ Tij_t,
         const int* __restrict__ edge_index,
         unsigned short* __restrict__ poseb, int* __restrict__ cnti,
         int* __restrict__ list, int E)
{
    const int g = blockIdx.x * 256 + threadIdx.x;
    if (g >= 2 * E) return;
    const bool fwd = (g < E);
    const int e = fwd ? g : g - E;
    const int ni = edge_index[e];
    const int nj = edge_index[E + e];
    const int tgt = fwd ? nj : ni;
    const int slot = atomicAdd(&cnti[tgt], 1);
    if (slot < MAXD) list[(size_t)tgt * MAXD + slot] = g;

    float Ri[9], Rj[9], TR[9], ti[3], tj[3], Tt[3];
#pragma unroll
    for (int q = 0; q < 9; q++) { Ri[q] = T_R[9*ni+q]; Rj[q] = T_R[9*nj+q]; TR[q] = Tij_R[9*e+q]; }
#pragma unroll
    for (int q = 0; q < 3; q++) { ti[q] = T_t[3*ni+q]; tj[q] = T_t[3*nj+q]; Tt[q] = Tij_t[3*e+q]; }
    float A[9];
    mul33_abt(Rj, Ri, A);   // A = Rj * Ri^T
    float Re[9], te[3];
    if (fwd) {
        mul33_abt(A, TR, Re);   // Reij = A * TR^T
#pragma unroll
        for (int r = 0; r < 3; r++)
            te[r] = tj[r]
                  - (A[3*r+0]*ti[0] + A[3*r+1]*ti[1] + A[3*r+2]*ti[2])
                  - (Re[3*r+0]*Tt[0] + Re[3*r+1]*Tt[1] + Re[3*r+2]*Tt[2]);
    } else {
#pragma unroll
        for (int r = 0; r < 3; r++)
#pragma unroll
            for (int c = 0; c < 3; c++)
                Re[3*r+c] = A[r]*TR[c] + A[3+r]*TR[3+c] + A[6+r]*TR[6+c];  // A^T * TR
        const float d0 = Tt[0]-tj[0], d1 = Tt[1]-tj[1], d2 = Tt[2]-tj[2];
#pragma unroll
        for (int r = 0; r < 3; r++)
            te[r] = ti[r] + A[r]*d0 + A[3+r]*d1 + A[6+r]*d2;
    }
    short8 p0, p1;
#pragma unroll
    for (int r = 0; r < 2; r++) {
        p0[4*r+0] = (short)f2b(Re[3*r+0]);
        p0[4*r+1] = (short)f2b(Re[3*r+1]);
        p0[4*r+2] = (short)f2b(Re[3*r+2]);
        p0[4*r+3] = (short)f2b(te[r]);
    }
    p1[0] = (short)f2b(Re[6]); p1[1] = (short)f2b(Re[7]);
    p1[2] = (short)f2b(Re[8]); p1[3] = (short)f2b(te[2]);
    p1[4] = 0; p1[5] = 0; p1[6] = 0; p1[7] = 0;
    *(short8*)(poseb + (size_t)g * 16) = p0;
    *(short8*)(poseb + (size_t)g * 16 + 8) = p1;
}

// Barrier-free edge MLP: 4 independent waves x 32 directions.
// A-fragments gathered directly from bf16 tables; only h1 round-trips via wave-private LDS.
__global__ void __launch_bounds__(256, 3)
edge_kernel(const unsigned short* __restrict__ xb, const unsigned short* __restrict__ eb,
            const unsigned short* __restrict__ poseb, const int* __restrict__ edge_index,
            const unsigned short* __restrict__ W1b, const float* __restrict__ b1,
            const unsigned short* __restrict__ W2b, const float* __restrict__ b2,
            unsigned short* __restrict__ hbuf, int E)
{
    __shared__ unsigned short h1s[4 * 32 * HP1];
    const int tid = threadIdx.x;
    const int wv = tid >> 6, lane = tid & 63;
    const int nl = lane & 15, quad = lane >> 4;
    const int D0 = blockIdx.x * MT + wv * 32;
    const int laneoff = quad * 128 + nl * 8;
    unsigned short* hw = h1s + wv * 32 * HP1;

    // per-lane indices for its two A-rows (m = nl and nl+16)
    int s1[2], s2[2], ee[2], gg[2];
#pragma unroll
    for (int rt = 0; rt < 2; rt++) {
        int g = D0 + rt * 16 + nl;
        if (g >= 2 * E) g = 2 * E - 1;
        const bool fwd = (g < E);
        const int e = fwd ? g : g - E;
        const int ni = edge_index[e];
        const int nj = edge_index[E + e];
        s1[rt] = fwd ? ni : nj;
        s2[rt] = fwd ? nj : ni;
        ee[rt] = e; gg[rt] = g;
    }

    // direct A-fragment gathers (16B each; 4 quad-lanes per row coalesce to 64B)
    short8 a[2][6];
#pragma unroll
    for (int rt = 0; rt < 2; rt++) {
        a[rt][0] = *(const short8*)(xb + (size_t)s1[rt] * ND + quad * 8);
        a[rt][1] = *(const short8*)(xb + (size_t)s1[rt] * ND + 32 + quad * 8);
        a[rt][2] = *(const short8*)(xb + (size_t)s2[rt] * ND + quad * 8);
        a[rt][3] = *(const short8*)(xb + (size_t)s2[rt] * ND + 32 + quad * 8);
        a[rt][4] = *(const short8*)(eb + (size_t)ee[rt] * ED + quad * 8);
        a[rt][5] = (quad < 2) ? *(const short8*)(poseb + (size_t)gg[rt] * 16 + quad * 8)
                              : (short8)(short)0;
    }

    float bias1[8], bias2[8];
#pragma unroll
    for (int nt = 0; nt < 8; nt++) { bias1[nt] = b1[nt*16 + nl]; bias2[nt] = b2[nt*16 + nl]; }

    f32x4 acc[2][8];
#pragma unroll
    for (int rt = 0; rt < 2; rt++)
#pragma unroll
        for (int nt = 0; nt < 8; nt++) acc[rt][nt] = (f32x4)0.f;

    // GEMM1: K = 192
#pragma unroll
    for (int kc = 0; kc < 6; kc++) {
#pragma unroll
        for (int nt = 0; nt < 8; nt++) {
            short8 b = *(const short8*)(W1b + (kc*8 + nt)*512 + laneoff);
            acc[0][nt] = __builtin_amdgcn_mfma_f32_16x16x32_bf16(a[0][kc], b, acc[0][nt], 0, 0, 0);
            acc[1][nt] = __builtin_amdgcn_mfma_f32_16x16x32_bf16(a[1][kc], b, acc[1][nt], 0, 0, 0);
        }
    }

    // h1: bias+relu -> wave-private LDS (C-layout -> A-layout round trip)
#pragma unroll
    for (int rt = 0; rt < 2; rt++)
#pragma unroll
        for (int nt = 0; nt < 8; nt++) {
            const int col = nt*16 + nl;
#pragma unroll
            for (int r = 0; r < 4; r++)
                hw[(rt*16 + quad*4 + r) * HP1 + col] = f2b(fmaxf(acc[rt][nt][r] + bias1[nt], 0.f));
        }
    // wave-local fence: LDS ops are in-order per wave; drain then read
    asm volatile("s_waitcnt lgkmcnt(0)" ::: "memory");

    // GEMM2: K = 128
#pragma unroll
    for (int rt = 0; rt < 2; rt++)
#pragma unroll
        for (int nt = 0; nt < 8; nt++) acc[rt][nt] = (f32x4)0.f;
#pragma unroll
    for (int kc = 0; kc < 4; kc++) {
        short8 a0 = *(const short8*)&hw[( 0 + nl) * HP1 + kc*32 + quad*8];
        short8 a1 = *(const short8*)&hw[(16 + nl) * HP1 + kc*32 + quad*8];
#pragma unroll
        for (int nt = 0; nt < 8; nt++) {
            short8 b = *(const short8*)(W2b + (kc*8 + nt)*512 + laneoff);
            acc[0][nt] = __builtin_amdgcn_mfma_f32_16x16x32_bf16(a0, b, acc[0][nt], 0, 0, 0);
            acc[1][nt] = __builtin_amdgcn_mfma_f32_16x16x32_bf16(a1, b, acc[1][nt], 0, 0, 0);
        }
    }

    // h2: relu + swizzled b128 store (pos nl*8+nt)
#pragma unroll
    for (int rt = 0; rt < 2; rt++)
#pragma unroll
        for (int r = 0; r < 4; r++) {
            const int g2 = D0 + rt*16 + quad*4 + r;
            if (g2 < 2 * E) {
                short8 hv;
#pragma unroll
                for (int nt = 0; nt < 8; nt++)
                    hv[nt] = (short)f2b(fmaxf(acc[rt][nt][r] + bias2[nt], 0.f));
                *(short8*)(hbuf + (size_t)g2 * HD + nl*8) = hv;
            }
        }
}

__global__ void __launch_bounds__(256)
node_kernel(const float* __restrict__ xfeat, const float* __restrict__ T_R,
            const float* __restrict__ T_t, const float* __restrict__ u,
            const int* __restrict__ batch,
            const unsigned short* __restrict__ W3b, const float* __restrict__ b3,
            const unsigned short* __restrict__ W4b, const float* __restrict__ b4,
            const unsigned short* __restrict__ hbuf, const int* __restrict__ list,
            const int* __restrict__ cnti,
            float* __restrict__ out, int Nn)
{
    __shared__ unsigned short gbuf[TDN * GP];
    __shared__ unsigned short hid[TDN * HP];
    __shared__ float obuf[TDN * OP];
    const int tid = threadIdx.x;
    const int wv = tid >> 6, lane = tid & 63;
    const int n0 = blockIdx.x * TDN;
    const int nn = min(TDN, Nn - n0);

    // gather+mean: wave wv owns nodes d = wv + 4i; lane covers positions 2*lane, 2*lane+1
#pragma unroll
    for (int i = 0; i < 4; i++) {
        const int d = wv + 4*i;
        if (d < nn) {
            const int n = n0 + d;
            const int deg = cnti[n];
            const int degl = min(deg, MAXD);
            const float inv = 1.0f / (float)max(deg, 1);
            const int* lp = list + (size_t)n * MAXD;
            float a0 = 0.f, a1 = 0.f;
            int k = 0;
            for (; k + 2 <= degl; k += 2) {
                const int e0 = lp[k], e1 = lp[k+1];
                const unsigned int v0 = *(const unsigned int*)(hbuf + (size_t)e0 * HD + 2*lane);
                const unsigned int v1 = *(const unsigned int*)(hbuf + (size_t)e1 * HD + 2*lane);
                a0 += b2f((unsigned short)v0) + b2f((unsigned short)v1);
                a1 += b2f((unsigned short)(v0 >> 16)) + b2f((unsigned short)(v1 >> 16));
            }
            if (k < degl) {
                const unsigned int v0 = *(const unsigned int*)(hbuf + (size_t)lp[k] * HD + 2*lane);
                a0 += b2f((unsigned short)v0);
                a1 += b2f((unsigned short)(v0 >> 16));
            }
            const unsigned int pk = (unsigned int)f2b(a0 * inv) | ((unsigned int)f2b(a1 * inv) << 16);
            *(unsigned int*)&gbuf[d * GP + 2*lane] = pk;
        }
    }
    for (int idx = tid; idx < TDN * 24; idx += 256) {
        const int d = idx / 24;
        if (d < nn) {
            const int n = n0 + d;
            const int c4 = (idx % 24) * 4;
            float4 v;
            if (c4 < 64) v = *(const float4*)&xfeat[(size_t)n * ND + c4];
            else         v = *(const float4*)&u[(size_t)batch[n] * GD + (c4 - 64)];
            ushort4 o; o.x = f2b(v.x); o.y = f2b(v.y); o.z = f2b(v.z); o.w = f2b(v.w);
            *(ushort4*)&gbuf[d * GP + 128 + c4] = o;
        }
    }
    __syncthreads();

    const int nl = lane & 15, quad = lane >> 4;
    const int laneoff = quad * 128 + nl * 8;

    // GEMM3: 16 rows, K=224; wave wv -> n-tiles {2wv, 2wv+1}
    f32x4 acc3[2];
    acc3[0] = (f32x4)0.f; acc3[1] = (f32x4)0.f;
#pragma unroll
    for (int kc = 0; kc < 7; kc++) {
        short8 A0 = *(const short8*)&gbuf[nl * GP + kc*32 + quad*8];
#pragma unroll
        for (int t = 0; t < 2; t++) {
            short8 B = *(const short8*)(W3b + (kc*8 + wv*2 + t)*512 + laneoff);
            acc3[t] = __builtin_amdgcn_mfma_f32_16x16x32_bf16(A0, B, acc3[t], 0, 0, 0);
        }
    }
#pragma unroll
    for (int t = 0; t < 2; t++) {
        const int col = (wv*2 + t)*16 + nl;
        const float bb = b3[col];
#pragma unroll
        for (int r = 0; r < 4; r++)
            hid[(quad*4 + r) * HP + col] = f2b(fmaxf(acc3[t][r] + bb, 0.f));
    }
    __syncthreads();

    // GEMM4: K=128, N=80 (5 n-tiles: wave w -> nt=w; wave0 also nt=4)
    f32x4 acc4[2];
    acc4[0] = (f32x4)0.f; acc4[1] = (f32x4)0.f;
    const int nt1 = (wv == 0) ? 4 : -1;
#pragma unroll
    for (int kc = 0; kc < 4; kc++) {
        short8 A0 = *(const short8*)&hid[nl * HP + kc*32 + quad*8];
        short8 B0 = *(const short8*)(W4b + (kc*5 + wv)*512 + laneoff);
        acc4[0] = __builtin_amdgcn_mfma_f32_16x16x32_bf16(A0, B0, acc4[0], 0, 0, 0);
        if (nt1 >= 0) {
            short8 B1 = *(const short8*)(W4b + (kc*5 + nt1)*512 + laneoff);
            acc4[1] = __builtin_amdgcn_mfma_f32_16x16x32_bf16(A0, B1, acc4[1], 0, 0, 0);
        }
    }
    {
        const int col0 = wv*16 + nl;
        const float bb0 = (col0 < NOUT) ? b4[col0] : 0.f;
#pragma unroll
        for (int r = 0; r < 4; r++)
            obuf[(quad*4 + r) * OP + col0] = acc4[0][r] + bb0;
        if (nt1 >= 0) {
            const int col1 = nt1*16 + nl;
            const float bb1 = (col1 < NOUT) ? b4[col1] : 0.f;
#pragma unroll
            for (int r = 0; r < 4; r++)
                obuf[(quad*4 + r) * OP + col1] = acc4[1][r] + bb1;
        }
    }
    __syncthreads();

    // xfeat residual
    for (int idx = tid; idx < TDN * ND; idx += 256) {
        const int d = idx >> 6, c = idx & 63;
        if (d < nn) {
            const int n = n0 + d;
            out[(size_t)n * OUTC + c] = xfeat[(size_t)n * ND + c] + obuf[d * OP + c];
        }
    }
    // SE(3) epilogue
    if (tid < nn) {
        const int n = n0 + tid;
        const float r0 = obuf[tid*OP + 64], r1 = obuf[tid*OP + 65], r2 = obuf[tid*OP + 66];
        float p0 = obuf[tid*OP + 67], p1 = obuf[tid*OP + 68], p2 = obuf[tid*OP + 69];
        const float th0 = sqrtf(p0*p0 + p1*p1 + p2*p2);
        const float s = PI_F * tanhf(th0 / PI_F) / (th0 + 1e-8f);
        p0 *= s; p1 *= s; p2 *= s;
        const float pp = p0*p0 + p1*p1 + p2*p2;
        const float th = sqrtf(pp + 1e-12f);
        float a, b, c;
        if (th < 1e-4f) { a = 1.f - pp/6.f; b = 0.5f - pp/24.f; c = 1.f/6.f - pp/120.f; }
        else { const float sn = sinf(th), cs = cosf(th); a = sn/th; b = (1.f-cs)/pp; c = (th-sn)/(pp*th); }
        float Rd[9], V[9];
        Rd[0]=1.f+b*(p0*p0-pp); Rd[1]=-a*p2+b*p0*p1; Rd[2]= a*p1+b*p0*p2;
        Rd[3]= a*p2+b*p1*p0;    Rd[4]=1.f+b*(p1*p1-pp); Rd[5]=-a*p0+b*p1*p2;
        Rd[6]=-a*p1+b*p2*p0;    Rd[7]= a*p0+b*p2*p1;  Rd[8]=1.f+b*(p2*p2-pp);
        V[0]=1.f+c*(p0*p0-pp);  V[1]=-b*p2+c*p0*p1;   V[2]= b*p1+c*p0*p2;
        V[3]= b*p2+c*p1*p0;     V[4]=1.f+c*(p1*p1-pp); V[5]=-b*p0+c*p1*p2;
        V[6]=-b*p1+c*p2*p0;     V[7]= b*p0+c*p2*p1;   V[8]=1.f+c*(p2*p2-pp);
        const float td0 = V[0]*r0 + V[1]*r1 + V[2]*r2;
        const float td1 = V[3]*r0 + V[4]*r1 + V[5]*r2;
        const float td2 = V[6]*r0 + V[7]*r1 + V[8]*r2;
        float TRn[9], Ttn[3];
#pragma unroll
        for (int q = 0; q < 9; q++) TRn[q] = T_R[9*n+q];
#pragma unroll
        for (int q = 0; q < 3; q++) Ttn[q] = T_t[3*n+q];
        float* o = out + (size_t)n * OUTC + 64;
#pragma unroll
        for (int r = 0; r < 3; r++)
#pragma unroll
            for (int cc = 0; cc < 3; cc++)
                o[3*r+cc] = Rd[3*r+0]*TRn[cc] + Rd[3*r+1]*TRn[3+cc] + Rd[3*r+2]*TRn[6+cc];
        o[9]  = Rd[0]*Ttn[0] + Rd[1]*Ttn[1] + Rd[2]*Ttn[2] + td0;
        o[10] = Rd[3]*Ttn[0] + Rd[4]*Ttn[1] + Rd[5]*Ttn[2] + td1;
        o[11] = Rd[6]*Ttn[0] + Rd[7]*Ttn[1] + Rd[8]*Ttn[2] + td2;
        o[12] = sqrtf(pp);
    }
}

extern "C" void kernel_launch(void* const* d_in, const int* in_sizes, int n_in,
                              void* d_out, int out_size, void* d_ws, size_t ws_size,
                              hipStream_t stream)
{
    const float* xfeat     = (const float*)d_in[0];
    const float* T_R       = (const float*)d_in[1];
    const float* T_t       = (const float*)d_in[2];
    const float* edge_feat = (const float*)d_in[3];
    const float* Tij_R     = (const float*)d_in[4];
    const float* Tij_t     = (const float*)d_in[5];
    const float* u         = (const float*)d_in[6];
    const int*   edge_index= (const int*)d_in[7];
    const int*   batch     = (const int*)d_in[8];
    const float* W1 = (const float*)d_in[9],  *b1 = (const float*)d_in[10];
    const float* W2 = (const float*)d_in[11], *b2 = (const float*)d_in[12];
    const float* W3 = (const float*)d_in[13], *b3 = (const float*)d_in[14];
    const float* W4 = (const float*)d_in[15], *b4 = (const float*)d_in[16];
    const int N = in_sizes[0] / ND;
    const int E = in_sizes[3] / ED;

    // ws: weights(bf16 frag) | xb | eb | poseb | hbuf | list | cnti
    char* p = (char*)d_ws;
    unsigned short* W1b = (unsigned short*)p;   p += (size_t)K1PAD * HD * 2;
    unsigned short* W2b = (unsigned short*)p;   p += (size_t)HD * HD * 2;
    unsigned short* W3b = (unsigned short*)p;   p += (size_t)KG * HD * 2;
    unsigned short* W4b = (unsigned short*)p;   p += (size_t)HD * N4P * 2;
    unsigned short* xb  = (unsigned short*)p;   p += (size_t)N * ND * 2;
    unsigned short* ebf = (unsigned short*)p;   p += (size_t)E * ED * 2;
    unsigned short* poseb = (unsigned short*)p; p += (size_t)2 * E * 16 * 2;
    unsigned short* hbuf = (unsigned short*)p;  p += (size_t)2 * E * HD * 2;
    int* list = (int*)p;                        p += (size_t)N * MAXD * 4;
    int* cnti = (int*)p;

    hipMemsetAsync(cnti, 0, (size_t)N * 4, stream);
    const int prepn = K1PAD*HD + HD*HD + KG*HD + HD*N4P + N*ND/4 + E*ED/4;
    prep<<<(prepn + 255) / 256, 256, 0, stream>>>(W1, W2, W3, W4, xfeat, edge_feat,
                                                  W1b, W2b, W3b, W4b, xb, ebf, N, E);
    pose_csr<<<(2*E + 255) / 256, 256, 0, stream>>>(T_R, T_t, Tij_R, Tij_t, edge_index,
                                                    poseb, cnti, list, E);
    const int ebk = (2 * E + MT - 1) / MT;
    edge_kernel<<<ebk, 256, 0, stream>>>(xb, ebf, poseb, edge_index,
                                         W1b, b1, W2b, b2, hbuf, E);
    const int nb = (N + TDN - 1) / TDN;
    node_kernel<<<nb, 256, 0, stream>>>(xfeat, T_R, T_t, u, batch, W3b, b3, W4b, b4,
                                        hbuf, list, cnti, (float*)d_out, N);
}